// Round 8
// baseline (603.211 us; speedup 1.0000x reference)
//
#include <hip/hip_runtime.h>
#include <hip/hip_bf16.h>

// ---------------- problem constants ----------------
#define NN 20000      // nodes
#define EE 640000     // edges
#define RR 65         // relations
#define FIN1 128      // input feat
#define HH1 64        // hidden1
#define HH2 32        // hidden2
#define BB 8192       // pairs

constexpr int BM = 128;                 // edge-tile rows per GEMM block
constexpr int NBH = 256;                // histogram/placement blocks
constexpr int GRID_PRE = 2048;          // k_hist launch grid (occupancy for conversions)
constexpr int EPB = EE / NBH;           // 2500 edges per block
constexpr int NBT = (NN + BM - 1) / BM; // 157 node tiles
constexpr int NOCT = 8;                 // src octiles (nodes per octile = 2500)
constexpr int NPO = NN / NOCT;          // 2500
constexpr int NB2 = NOCT * RR;          // 520 sort buckets (octile-major, relation inner)
constexpr int MAXT2 = EE / BM + NB2;    // 5520 tile upper bound

// classifier GEMM geometry (E[8192x448] @ clsW[448x65], padded)
constexpr int CLS_K  = 512;
constexpr int CLS_N  = 80;
constexpr int CLS_CK = 128;
constexpr int CLS_BM = 64;

typedef __attribute__((ext_vector_type(8))) short short8;   // 8 bf16 MFMA frag
typedef __attribute__((ext_vector_type(4))) float floatx4;  // 4 fp32 acc
typedef __attribute__((ext_vector_type(4))) unsigned int uint4e;  // 16B vector
typedef __attribute__((ext_vector_type(2))) unsigned int uint2e;  // 8B vector

// ---------------- workspace layout (bytes) ----------------
constexpr size_t aln(size_t x) { return (x + 255) & ~(size_t)255; }

constexpr size_t OFF_CSUM  = 0;                        // 32 f
constexpr size_t OFF_CNTD  = aln(OFF_CSUM + 32 * 4);  // NN int (dst degree)
constexpr size_t ZERO_BYTES = OFF_CNTD + (size_t)NN * 4;   // memset [0, ZERO_BYTES)
constexpr size_t OFF_DSTOFF = aln(ZERO_BYTES);         // NN+1 int
constexpr size_t OFF_BH0   = aln(OFF_DSTOFF + ((size_t)NN + 1) * 4); // NBH*NB2
constexpr size_t OFF_BH1   = OFF_BH0 + (size_t)NBH * NB2 * 4;
constexpr size_t OFF_BB0   = OFF_BH1 + (size_t)NBH * NB2 * 4;
constexpr size_t OFF_BB1   = OFF_BB0 + (size_t)NBH * NB2 * 4;
constexpr size_t OFF_HT    = aln(OFF_BB1 + (size_t)NBH * NB2 * 4);   // 2*NB2 int totals
constexpr size_t OFF_OFFB0 = aln(OFF_HT + (size_t)2 * NB2 * 4);      // NB2+1 int
constexpr size_t OFF_OFFB1 = OFF_OFFB0 + (NB2 + 1) * 4;
constexpr size_t OFF_TILB0 = aln(OFF_OFFB1 + (NB2 + 1) * 4);  // MAXT2 int
constexpr size_t OFF_TILT0 = OFF_TILB0 + (size_t)MAXT2 * 4;
constexpr size_t OFF_TILB1 = OFF_TILT0 + (size_t)MAXT2 * 4;
constexpr size_t OFF_TILT1 = OFF_TILB1 + (size_t)MAXT2 * 4;
constexpr size_t OFF_SLOT  = aln(OFF_TILT1 + (size_t)MAXT2 * 4);  // E int
constexpr size_t OFF_POSD  = OFF_SLOT + (size_t)EE * 4;           // E int (e -> dst pos)
constexpr size_t OFF_RDP   = OFF_POSD + (size_t)EE * 4;           // E uint (pos -> r0|r1<<16)
constexpr size_t OFF_WD0   = OFF_RDP + (size_t)EE * 4;            // E float (pos-space weights)
constexpr size_t OFF_WD1   = OFF_WD0 + (size_t)EE * 4;
constexpr size_t OFF_PERM0 = OFF_WD1 + (size_t)EE * 4;            // E uint (srcLocal<<20|pos)
constexpr size_t OFF_PERM1 = OFF_PERM0 + (size_t)EE * 4;
constexpr size_t OFF_XOB   = aln(OFF_PERM1 + (size_t)EE * 4);     // N*F bf16
constexpr size_t OFF_XAB   = OFF_XOB + (size_t)NN * FIN1 * 2;
constexpr size_t OFF_H1    = aln(OFF_XAB + (size_t)NN * FIN1 * 2); // 3 * N*64 f
constexpr size_t OFF_H1B   = OFF_H1 + (size_t)3 * NN * HH1 * 4;    // 3 * N*64 bf16
constexpr size_t OFF_X2A   = OFF_H1B + (size_t)3 * NN * HH1 * 2;   // N*32 f
constexpr size_t OFF_X2AA  = OFF_X2A + (size_t)NN * HH2 * 4;
constexpr size_t OFF_W1BT  = OFF_X2AA + (size_t)NN * HH2 * 4;      // R*64*128 bf16
constexpr size_t OFF_W2BT  = OFF_W1BT + (size_t)RR * HH1 * FIN1 * 2;
constexpr size_t OFF_R1T   = OFF_W2BT + (size_t)RR * HH2 * HH1 * 2;
constexpr size_t OFF_R2T   = OFF_R1T + (size_t)HH1 * FIN1 * 2;
constexpr size_t OFF_CWT   = OFF_R2T + (size_t)HH2 * HH1 * 2;
constexpr size_t OFF_PART  = aln(OFF_CWT + (size_t)CLS_N * CLS_K * 2); // 256*32 f partials
constexpr size_t OFF_MSG   = aln(OFF_PART + (size_t)256 * 32 * 4);     // msg buffers (1..2)
constexpr size_t MSG_B1    = (size_t)EE * HH1 * 2;   // one layer-1 msg buffer
constexpr size_t MSG_B2    = (size_t)EE * HH2 * 2;   // one layer-2 msg buffer
constexpr size_t WS_END    = OFF_MSG + MSG_B1;       // minimum required (1 buffer)

// output offsets (floats)
constexpr size_t O_LOG  = 0;
constexpr size_t O_ROS  = (size_t)BB * RR;
constexpr size_t O_ROSA = O_ROS + (size_t)NN * 2;
constexpr size_t O_X2O  = O_ROSA + (size_t)NN * 2;

__device__ inline unsigned short f2bf(float f) {
    __hip_bfloat16 h = __float2bfloat16(f);
    return *reinterpret_cast<unsigned short*>(&h);
}
__device__ inline float bfbits2f(unsigned int hi_bits) {
    return __uint_as_float(hi_bits);
}

struct RedEnc {
    const unsigned short* msg;
    const float* wD;
    float* base;
    unsigned short* bfout;
};
struct RedArgs { RedEnc e[3]; };

// ---------------- preprocessing ----------------
// blocks < NBH: per-block 520-bin (octile,relation) histograms via LDS,
// per-dst degree + slot. ALL blocks: vectorized streaming bf16 conversions.
__global__ void k_hist(const int* __restrict__ ei, const int* __restrict__ et0,
                       const int* __restrict__ et1,
                       int* cntD, int* __restrict__ slotE,
                       int* __restrict__ bh0, int* __restrict__ bh1,
                       const float* __restrict__ x_o, const float* __restrict__ x_a,
                       const float* __restrict__ W1, const float* __restrict__ W2,
                       const float* __restrict__ root1, const float* __restrict__ root2,
                       const float* __restrict__ clsW,
                       unsigned short* xob, unsigned short* xab,
                       unsigned short* w1t, unsigned short* w2t,
                       unsigned short* r1t, unsigned short* r2t,
                       unsigned short* cwt) {
    __shared__ int lh0[NB2], lh1[NB2];
    int t = threadIdx.x;
    if (blockIdx.x < NBH) {
        for (int p = t; p < NB2; p += 256) { lh0[p] = 0; lh1[p] = 0; }
        __syncthreads();
        int base = blockIdx.x * EPB;
        for (int i = t; i < EPB; i += 256) {
            int e = base + i;
            int oct = ei[e] / NPO;
            atomicAdd(&lh0[oct * RR + et0[e]], 1);
            atomicAdd(&lh1[oct * RR + et1[e]], 1);
            slotE[e] = atomicAdd(&cntD[ei[EE + e]], 1);
        }
        __syncthreads();
        for (int p = t; p < NB2; p += 256) {
            bh0[blockIdx.x * NB2 + p] = lh0[p];
            bh1[blockIdx.x * NB2 + p] = lh1[p];
        }
    }
    // streaming conversions (grid-stride, vectorized 4-wide)
    int stride = gridDim.x * 256;
    int i0 = blockIdx.x * 256 + t;
    const int NX4 = NN * FIN1 / 4;
    const float4* xo4 = (const float4*)x_o;
    const float4* xa4 = (const float4*)x_a;
    for (int i = i0; i < NX4; i += stride) {
        float4 a = xo4[i], b = xa4[i];
        uint2 pa, pb;
        pa.x = (unsigned)f2bf(a.x) | ((unsigned)f2bf(a.y) << 16);
        pa.y = (unsigned)f2bf(a.z) | ((unsigned)f2bf(a.w) << 16);
        pb.x = (unsigned)f2bf(b.x) | ((unsigned)f2bf(b.y) << 16);
        pb.y = (unsigned)f2bf(b.z) | ((unsigned)f2bf(b.w) << 16);
        ((uint2*)xob)[i] = pa;
        ((uint2*)xab)[i] = pb;
    }
    const int NW1_4 = RR * HH1 * FIN1 / 4;
    for (int i4 = i0; i4 < NW1_4; i4 += stride) {
        int i = i4 * 4;
        int k = i % FIN1; int rh = i / FIN1; int hh = rh % HH1; int r = rh / HH1;
        const float* s = &W1[((size_t)r * FIN1 + k) * HH1 + hh];
        uint2 pk;
        pk.x = (unsigned)f2bf(s[0]) | ((unsigned)f2bf(s[HH1]) << 16);
        pk.y = (unsigned)f2bf(s[2 * HH1]) | ((unsigned)f2bf(s[3 * HH1]) << 16);
        ((uint2*)w1t)[i4] = pk;
    }
    const int NW2_4 = RR * HH2 * HH1 / 4;
    for (int i4 = i0; i4 < NW2_4; i4 += stride) {
        int i = i4 * 4;
        int k = i % HH1; int rh = i / HH1; int hh = rh % HH2; int r = rh / HH2;
        const float* s = &W2[((size_t)r * HH1 + k) * HH2 + hh];
        uint2 pk;
        pk.x = (unsigned)f2bf(s[0]) | ((unsigned)f2bf(s[HH2]) << 16);
        pk.y = (unsigned)f2bf(s[2 * HH2]) | ((unsigned)f2bf(s[3 * HH2]) << 16);
        ((uint2*)w2t)[i4] = pk;
    }
    const int NR1_4 = HH1 * FIN1 / 4;
    for (int i4 = i0; i4 < NR1_4; i4 += stride) {
        int i = i4 * 4;
        int k = i % FIN1; int hh = i / FIN1;
        const float* s = &root1[(size_t)k * HH1 + hh];
        uint2 pk;
        pk.x = (unsigned)f2bf(s[0]) | ((unsigned)f2bf(s[HH1]) << 16);
        pk.y = (unsigned)f2bf(s[2 * HH1]) | ((unsigned)f2bf(s[3 * HH1]) << 16);
        ((uint2*)r1t)[i4] = pk;
    }
    const int NR2_4 = HH2 * HH1 / 4;
    for (int i4 = i0; i4 < NR2_4; i4 += stride) {
        int i = i4 * 4;
        int k = i % HH1; int hh = i / HH1;
        const float* s = &root2[(size_t)k * HH2 + hh];
        uint2 pk;
        pk.x = (unsigned)f2bf(s[0]) | ((unsigned)f2bf(s[HH2]) << 16);
        pk.y = (unsigned)f2bf(s[2 * HH2]) | ((unsigned)f2bf(s[3 * HH2]) << 16);
        ((uint2*)r2t)[i4] = pk;
    }
    const int NCW_4 = CLS_N * CLS_K / 4;
    for (int i4 = i0; i4 < NCW_4; i4 += stride) {
        int i = i4 * 4;
        int k = i % CLS_K; int n = i / CLS_K;
        uint2 pk = {0u, 0u};
        if (n < RR && k < 448) {
            const float* s = &clsW[(size_t)k * RR + n];
            pk.x = (unsigned)f2bf(s[0]) | ((unsigned)f2bf(s[RR]) << 16);
            pk.y = (unsigned)f2bf(s[2 * RR]) | ((unsigned)f2bf(s[3 * RR]) << 16);
        }
        ((uint2*)cwt)[i4] = pk;
    }
}

// exclusive scan of per-dst degrees -> dstOff[NN+1] (single block)
__global__ void k_scanD(const int* __restrict__ cntD, int* __restrict__ dstOff) {
    __shared__ int s[256];
    int t = threadIdx.x;
    constexpr int PER = (NN + 255) / 256;
    int lo = t * PER, hi = min(NN, lo + PER);
    int sum = 0;
    for (int i = lo; i < hi; i++) sum += cntD[i];
    s[t] = sum;
    __syncthreads();
    for (int ofs = 1; ofs < 256; ofs <<= 1) {
        int v = 0;
        if (t >= ofs) v = s[t - ofs];
        __syncthreads();
        if (t >= ofs) s[t] += v;
        __syncthreads();
    }
    int run = s[t] - sum;
    for (int i = lo; i < hi; i++) { dstOff[i] = run; run += cntD[i]; }
    if (t == 255) dstOff[NN] = run;
}

// posD (sequential write) + rdP (the single scattered-write array)
__global__ void k_post(const int* __restrict__ ei, const int* __restrict__ et0,
                       const int* __restrict__ et1, const int* __restrict__ dstOff,
                       const int* __restrict__ slotE,
                       int* __restrict__ posD, unsigned int* __restrict__ rdP) {
    int e = blockIdx.x * 256 + threadIdx.x;
    if (e < EE) {
        int d = ei[EE + e];
        int pos = dstOff[d] + slotE[e];
        posD[e] = pos;
        rdP[pos] = (unsigned)et0[e] | ((unsigned)et1[e] << 16);
    }
}

// phase 1: per-bucket exclusive prefix over the 256 histogram blocks.
__global__ void k_scanB1(const int* __restrict__ bh0, const int* __restrict__ bh1,
                         int* __restrict__ bb0, int* __restrict__ bb1,
                         int* __restrict__ hT) {
    int w = (blockIdx.x * 256 + threadIdx.x) >> 6;
    int lane = threadIdx.x & 63;
    if (w >= 2 * NB2) return;
    int s = w / NB2, k = w % NB2;
    const int* bh = s ? bh1 : bh0;
    int* bb = s ? bb1 : bb0;
    int v[4];
    #pragma unroll
    for (int i = 0; i < 4; i++) v[i] = bh[(size_t)(lane * 4 + i) * NB2 + k];
    int ls = v[0] + v[1] + v[2] + v[3];
    int inc = ls;
    #pragma unroll
    for (int ofs = 1; ofs < 64; ofs <<= 1) {
        int o = __shfl_up(inc, ofs);
        if (lane >= ofs) inc += o;
    }
    int run = inc - ls;   // exclusive base for this lane
    #pragma unroll
    for (int i = 0; i < 4; i++) {
        bb[(size_t)(lane * 4 + i) * NB2 + k] = run;
        run += v[i];
    }
    if (lane == 63) hT[s * NB2 + k] = run;  // column total
}

// phase 2 (single block): bucket offsets + tile tables from the 1040 totals.
__global__ void k_scanB2(const int* __restrict__ hT,
                         int* offB0, int* offB1,
                         int* tilB0, int* tilT0, int* tilB1, int* tilT1) {
    __shared__ int h[2][NB2];
    __shared__ int o[2][NB2 + 1];
    __shared__ int to[2][NB2 + 1];
    __shared__ int csumE[2][8], csumT[2][8];
    int t = threadIdx.x;
    for (int p = t; p < 2 * NB2; p += 256) h[p / NB2][p % NB2] = hT[p];
    __syncthreads();
    if (t < 16) {
        int s = t / 8, c = t % 8;
        int runE = 0, runT = 0;
        for (int k = c * RR; k < (c + 1) * RR; k++) {
            o[s][k] = runE;  runE += h[s][k];
            to[s][k] = runT; runT += (h[s][k] + BM - 1) / BM;
        }
        csumE[s][c] = runE; csumT[s][c] = runT;
    }
    __syncthreads();
    if (t < 2) {
        int runE = 0, runT = 0;
        for (int c = 0; c < 8; c++) {
            int e = csumE[t][c], tt = csumT[t][c];
            csumE[t][c] = runE; csumT[t][c] = runT;
            runE += e; runT += tt;
        }
        o[t][NB2] = runE; to[t][NB2] = runT;
    }
    __syncthreads();
    if (t < 16) {
        int s = t / 8, c = t % 8;
        for (int k = c * RR; k < (c + 1) * RR; k++) {
            o[s][k] += csumE[s][c];
            to[s][k] += csumT[s][c];
        }
    }
    __syncthreads();
    for (int p = t; p <= NB2; p += 256) { offB0[p] = o[0][p]; offB1[p] = o[1][p]; }
    for (int i = t; i < MAXT2; i += 256) {
        #pragma unroll
        for (int s = 0; s < 2; s++) {
            int total = to[s][NB2];
            int bkt = -1, ti = 0;
            if (i < total) {
                int lo = 0, hi = NB2;
                while (hi - lo > 1) { int mid = (lo + hi) >> 1; if (to[s][mid] <= i) lo = mid; else hi = mid; }
                bkt = lo;
                ti = i - to[s][lo];
            }
            if (s == 0) { tilB0[i] = bkt; tilT0[i] = ti; }
            else        { tilB1[i] = bkt; tilT1[i] = ti; }
        }
    }
}

// bucket-sorted perm placement with deterministic bases.
__global__ void k_fillB(const int* __restrict__ ei, const int* __restrict__ et0,
                        const int* __restrict__ et1, const int* __restrict__ posD,
                        const int* __restrict__ offB0, const int* __restrict__ offB1,
                        const int* __restrict__ bb0, const int* __restrict__ bb1,
                        unsigned int* perm0, unsigned int* perm1) {
    __shared__ int lc[2][NB2];
    __shared__ int lb[2][NB2];
    int t = threadIdx.x;
    for (int p = t; p < NB2; p += 256) {
        lc[0][p] = 0; lc[1][p] = 0;
        lb[0][p] = offB0[p] + bb0[blockIdx.x * NB2 + p];
        lb[1][p] = offB1[p] + bb1[blockIdx.x * NB2 + p];
    }
    __syncthreads();
    int base = blockIdx.x * EPB;
    for (int i = t; i < EPB; i += 256) {
        int e = base + i;
        int src = ei[e];                 // sequential read
        int pos = posD[e];               // sequential read
        int oct = src / NPO;
        unsigned int packed = ((unsigned)(src - oct * NPO) << 20) | (unsigned)pos;
        int k0 = oct * RR + et0[e];
        int k1 = oct * RR + et1[e];
        int p0 = atomicAdd(&lc[0][k0], 1);
        int p1 = atomicAdd(&lc[1][k1], 1);
        perm0[lb[0][k0] + p0] = packed;
        perm1[lb[1][k1] + p1] = packed;
    }
}

// per-(relation,dst) mean weights inside each dst segment -> pos-space arrays
__global__ void k_wts(const int* __restrict__ dstOff, const unsigned int* __restrict__ rdP,
                      float* __restrict__ wD0, float* __restrict__ wD1) {
    constexpr int CAP = 96;
    __shared__ unsigned int ld[4][CAP];
    int wave = threadIdx.x >> 6;
    int lane = threadIdx.x & 63;
    int d = blockIdx.x * 4 + wave;
    int j0 = 0, deg = 0;
    if (d < NN) { j0 = dstOff[d]; deg = dstOff[d + 1] - j0; }
    for (int j = lane; j < deg && j < CAP; j += 64) ld[wave][j] = rdP[j0 + j];
    __syncthreads();
    for (int j = lane; j < deg; j += 64) {
        unsigned int my = (j < CAP) ? ld[wave][j] : rdP[j0 + j];
        unsigned int m0 = my & 0xffffu, m1 = my >> 16;
        int c0 = 0, c1 = 0;
        for (int k = 0; k < deg; k++) {
            unsigned int p = (k < CAP) ? ld[wave][k] : rdP[j0 + k];
            c0 += ((p & 0xffffu) == m0);
            c1 += ((p >> 16) == m1);
        }
        wD0[j0 + j] = 1.0f / (float)c0;
        wD1[j0 + j] = 1.0f / (float)c1;
    }
}

// root-term GEMM via MFMA: O[n,h] = Xb[n,:] @ rootT[h,:] + bias[h]  (fp32 out)
template <int FIN, int HOUT>
__launch_bounds__(256, 3)
__global__ void k_bgemm(const unsigned short* __restrict__ X0,
                        const unsigned short* __restrict__ X1,
                        const unsigned short* __restrict__ X2,
                        const unsigned short* __restrict__ rootT,
                        const float* __restrict__ bias,
                        float* O0, float* O1, float* O2) {
    const int enc = blockIdx.y;
    const unsigned short* X = enc == 0 ? X0 : enc == 1 ? X1 : X2;
    float* O = enc == 0 ? O0 : enc == 1 ? O1 : O2;
    int n0 = blockIdx.x * BM;
    int mcount = min(BM, NN - n0);

    constexpr int LDK = FIN + 8;
    __shared__ unsigned short As[BM][LDK];
    __shared__ unsigned short Bs[HOUT][LDK];

    int tid = threadIdx.x;
    {
        constexpr int CHB = HOUT * FIN / 8;
        for (int c = tid; c < CHB; c += 256) {
            int row = c / (FIN / 8), cc = c % (FIN / 8);
            *(uint4*)&Bs[row][cc * 8] = *(const uint4*)&rootT[row * FIN + cc * 8];
        }
    }
    {
        constexpr int CHA = BM * FIN / 8;
        for (int c = tid; c < CHA; c += 256) {
            int row = c / (FIN / 8), cc = c % (FIN / 8);
            uint4 v = {0u, 0u, 0u, 0u};
            if (row < mcount) v = *(const uint4*)&X[(size_t)(n0 + row) * FIN + cc * 8];
            *(uint4*)&As[row][cc * 8] = v;
        }
    }
    __syncthreads();

    const int wave = tid >> 6;
    const int lane = tid & 63;
    const int q = lane >> 4;
    const int ln = lane & 15;
    constexpr int NT = HOUT / 16;
    constexpr int KS = FIN / 32;
    const int mbase = wave * 32;

    floatx4 acc[2][NT];
    #pragma unroll
    for (int a = 0; a < 2; a++)
        #pragma unroll
        for (int nt = 0; nt < NT; nt++) acc[a][nt] = floatx4{0.f, 0.f, 0.f, 0.f};

    for (int ks = 0; ks < KS; ks++) {
        int kk = ks * 32 + q * 8;
        short8 af0 = *(const short8*)&As[mbase + ln][kk];
        short8 af1 = *(const short8*)&As[mbase + 16 + ln][kk];
        #pragma unroll
        for (int nt = 0; nt < NT; nt++) {
            short8 bf = *(const short8*)&Bs[nt * 16 + ln][kk];
            acc[0][nt] = __builtin_amdgcn_mfma_f32_16x16x32_bf16(af0, bf, acc[0][nt], 0, 0, 0);
            acc[1][nt] = __builtin_amdgcn_mfma_f32_16x16x32_bf16(af1, bf, acc[1][nt], 0, 0, 0);
        }
    }

    #pragma unroll
    for (int mt = 0; mt < 2; mt++) {
        #pragma unroll
        for (int rr2 = 0; rr2 < 4; rr2++) {
            int i = mbase + mt * 16 + q * 4 + rr2;
            int n = n0 + i;
            if (i < mcount) {
                #pragma unroll
                for (int nt = 0; nt < NT; nt++)
                    O[(size_t)n * HOUT + nt * 16 + ln] = acc[mt][nt][rr2] + bias[nt * 16 + ln];
            }
        }
    }
}

// R7 single-X gather-GEMM: A fragments to registers (compiler sinks the
// loads into the MFMA loop — harmless with B in LDS), B staged in LDS,
// LDS ~19.4 KB -> high occupancy. Used for enc2 and the low-ws fallback.
template <int FIN, int HOUT>
__launch_bounds__(512, 8)
__global__ void k_gemm(const unsigned short* __restrict__ X,
                       unsigned short* __restrict__ msg,
                       const unsigned int* __restrict__ perm,
                       const int* __restrict__ offB,
                       const int* __restrict__ tilB, const int* __restrict__ tilT,
                       const unsigned short* __restrict__ WT) {
    int b = blockIdx.x;
    int bkt = tilB[b];
    if (bkt < 0) return;
    int r = bkt % RR;
    int srcBase = (bkt / RR) * NPO;
    int t = tilT[b];
    int ebase = offB[bkt] + t * BM;
    int mcount = min(BM, offB[bkt + 1] - ebase);

    constexpr int LDK = FIN + 8;
    constexpr int LDM = HOUT + 8;
    constexpr int BSZ = HOUT * LDK;
    constexpr int MSZ = BM * LDM;
    constexpr int USZ = BSZ > MSZ ? BSZ : MSZ;
    __shared__ unsigned short Us[USZ];   // Bs during K-loop, Ms in epilogue
    __shared__ int Sr[BM];
    __shared__ int Pd[BM];

    int tid = threadIdx.x;
    if (tid < BM) {
        if (tid < mcount) {
            unsigned int p = perm[ebase + tid];   // sequential
            Sr[tid] = srcBase + (int)(p >> 20);
            Pd[tid] = (int)(p & 0xFFFFFu);
        } else { Sr[tid] = -1; Pd[tid] = 0; }
    }
    {
        const unsigned short* Wr = WT + (size_t)r * HOUT * FIN;
        constexpr int CHB = HOUT * FIN / 8;
        for (int c = tid; c < CHB; c += 512) {
            int row = c / (FIN / 8), cc = c % (FIN / 8);
            *(uint4*)&Us[row * LDK + cc * 8] = *(const uint4*)&Wr[row * FIN + cc * 8];
        }
    }
    __syncthreads();

    const int wave = tid >> 6;
    const int lane = tid & 63;
    const int q = lane >> 4;
    const int ln = lane & 15;
    constexpr int NT = HOUT / 16;
    constexpr int KS = FIN / 32;
    const int mbase = wave * 16;

    int s = Sr[mbase + ln];
    short8 A[KS];
    #pragma unroll
    for (int ks = 0; ks < KS; ks++) A[ks] = short8{0,0,0,0,0,0,0,0};
    if (s >= 0) {
        const unsigned short* ap = X + (size_t)s * FIN + q * 8;
        #pragma unroll
        for (int ks = 0; ks < KS; ks++) A[ks] = *(const short8*)(ap + ks * 32);
    }

    floatx4 acc[NT];
    #pragma unroll
    for (int nt = 0; nt < NT; nt++) acc[nt] = floatx4{0.f, 0.f, 0.f, 0.f};

    #pragma unroll
    for (int ks = 0; ks < KS; ks++) {
        int kk = ks * 32 + q * 8;
        #pragma unroll
        for (int nt = 0; nt < NT; nt++) {
            short8 bf = *(const short8*)&Us[(nt * 16 + ln) * LDK + kk];
            acc[nt] = __builtin_amdgcn_mfma_f32_16x16x32_bf16(A[ks], bf, acc[nt], 0, 0, 0);
        }
    }

    __syncthreads();
    #pragma unroll
    for (int rr2 = 0; rr2 < 4; rr2++) {
        int i = mbase + q * 4 + rr2;
        #pragma unroll
        for (int nt = 0; nt < NT; nt++)
            Us[i * LDM + nt * 16 + ln] = f2bf(acc[nt][rr2]);
    }
    __syncthreads();
    constexpr int CH = HOUT / 8;
    for (int c = tid; c < BM * CH; c += 512) {
        int row = c / CH, cc = c % CH;
        if (row < mcount) {
            uint4e v = *(const uint4e*)&Us[row * LDM + cc * 8];
            *(uint4e*)&msg[(size_t)Pd[row] * HOUT + cc * 8] = v;
        }
    }
}

// PAIRED gather-GEMM: enc0 and enc1 share the same perm/tile tables AND the
// same per-relation B tile (only X differs: x_o vs x_a / h1bo vs h1ba).
// One block stages Sr/Pd/B ONCE and computes both A-tiles -> half the
// blocks, half the staging traffic, 2x MFMA per staged byte (R7 showed
// blocks are staging/latency-dominated: 15K cyc/generation vs ~3K work).
// Accumulation chains per output are instruction-identical to the single-X
// kernel -> bitwise-identical msg. Epilogue runs twice, reusing Us.
template <int FIN, int HOUT>
__launch_bounds__(512, 8)
__global__ void k_gemm2(const unsigned short* __restrict__ X0,
                        const unsigned short* __restrict__ X1,
                        unsigned short* __restrict__ msg0,
                        unsigned short* __restrict__ msg1,
                        const unsigned int* __restrict__ perm,
                        const int* __restrict__ offB,
                        const int* __restrict__ tilB, const int* __restrict__ tilT,
                        const unsigned short* __restrict__ WT) {
    int b = blockIdx.x;
    int bkt = tilB[b];
    if (bkt < 0) return;
    int r = bkt % RR;
    int srcBase = (bkt / RR) * NPO;
    int t = tilT[b];
    int ebase = offB[bkt] + t * BM;
    int mcount = min(BM, offB[bkt + 1] - ebase);

    constexpr int LDK = FIN + 8;
    constexpr int LDM = HOUT + 8;
    constexpr int BSZ = HOUT * LDK;
    constexpr int MSZ = BM * LDM;
    constexpr int USZ = BSZ > MSZ ? BSZ : MSZ;
    __shared__ unsigned short Us[USZ];
    __shared__ int Sr[BM];
    __shared__ int Pd[BM];

    int tid = threadIdx.x;
    if (tid < BM) {
        if (tid < mcount) {
            unsigned int p = perm[ebase + tid];
            Sr[tid] = srcBase + (int)(p >> 20);
            Pd[tid] = (int)(p & 0xFFFFFu);
        } else { Sr[tid] = -1; Pd[tid] = 0; }
    }
    {
        const unsigned short* Wr = WT + (size_t)r * HOUT * FIN;
        constexpr int CHB = HOUT * FIN / 8;
        for (int c = tid; c < CHB; c += 512) {
            int row = c / (FIN / 8), cc = c % (FIN / 8);
            *(uint4*)&Us[row * LDK + cc * 8] = *(const uint4*)&Wr[row * FIN + cc * 8];
        }
    }
    __syncthreads();

    const int wave = tid >> 6;
    const int lane = tid & 63;
    const int q = lane >> 4;
    const int ln = lane & 15;
    constexpr int NT = HOUT / 16;
    constexpr int KS = FIN / 32;
    const int mbase = wave * 16;

    int s = Sr[mbase + ln];
    short8 A0[KS], A1[KS];
    #pragma unroll
    for (int ks = 0; ks < KS; ks++) {
        A0[ks] = short8{0,0,0,0,0,0,0,0};
        A1[ks] = short8{0,0,0,0,0,0,0,0};
    }
    if (s >= 0) {
        const unsigned short* a0p = X0 + (size_t)s * FIN + q * 8;
        const unsigned short* a1p = X1 + (size_t)s * FIN + q * 8;
        #pragma unroll
        for (int ks = 0; ks < KS; ks++) {
            A0[ks] = *(const short8*)(a0p + ks * 32);
            A1[ks] = *(const short8*)(a1p + ks * 32);
        }
    }

    floatx4 acc0[NT], acc1[NT];
    #pragma unroll
    for (int nt = 0; nt < NT; nt++) {
        acc0[nt] = floatx4{0.f, 0.f, 0.f, 0.f};
        acc1[nt] = floatx4{0.f, 0.f, 0.f, 0.f};
    }

    #pragma unroll
    for (int ks = 0; ks < KS; ks++) {
        int kk = ks * 32 + q * 8;
        #pragma unroll
        for (int nt = 0; nt < NT; nt++) {
            short8 bf = *(const short8*)&Us[(nt * 16 + ln) * LDK + kk];
            acc0[nt] = __builtin_amdgcn_mfma_f32_16x16x32_bf16(A0[ks], bf, acc0[nt], 0, 0, 0);
            acc1[nt] = __builtin_amdgcn_mfma_f32_16x16x32_bf16(A1[ks], bf, acc1[nt], 0, 0, 0);
        }
    }

    constexpr int CH = HOUT / 8;
    // epilogue pass 0 (msg0)
    __syncthreads();
    #pragma unroll
    for (int rr2 = 0; rr2 < 4; rr2++) {
        int i = mbase + q * 4 + rr2;
        #pragma unroll
        for (int nt = 0; nt < NT; nt++)
            Us[i * LDM + nt * 16 + ln] = f2bf(acc0[nt][rr2]);
    }
    __syncthreads();
    for (int c = tid; c < BM * CH; c += 512) {
        int row = c / CH, cc = c % CH;
        if (row < mcount) {
            uint4e v = *(const uint4e*)&Us[row * LDM + cc * 8];
            *(uint4e*)&msg0[(size_t)Pd[row] * HOUT + cc * 8] = v;
        }
    }
    // epilogue pass 1 (msg1)
    __syncthreads();
    #pragma unroll
    for (int rr2 = 0; rr2 < 4; rr2++) {
        int i = mbase + q * 4 + rr2;
        #pragma unroll
        for (int nt = 0; nt < NT; nt++)
            Us[i * LDM + nt * 16 + ln] = f2bf(acc1[nt][rr2]);
    }
    __syncthreads();
    for (int c = tid; c < BM * CH; c += 512) {
        int row = c / CH, cc = c % CH;
        if (row < mcount) {
            uint4e v = *(const uint4e*)&Us[row * LDM + cc * 8];
            *(uint4e*)&msg1[(size_t)Pd[row] * HOUT + cc * 8] = v;
        }
    }
}

// weighted segment-sum of msg rows per dst + root base; optional relu+bf16.
// DOUBLE accumulation keeps results independent of the (nondeterministic)
// edge->slot assignment order. blockIdx.y selects the encoding bundle.
template <int H, bool RELU>
__global__ void k_reduce(RedArgs ra, const int* __restrict__ dstOff) {
    const RedEnc re = ra.e[blockIdx.y];
    int d = blockIdx.x * 4 + (threadIdx.x >> 6);
    if (d >= NN) return;
    int lane = threadIdx.x & 63;
    constexpr int HC = H / 4;
    constexpr int RPI = 64 / HC;
    int sub = lane / HC;
    int c4 = lane % HC;
    int j0 = dstOff[d], j1 = dstOff[d + 1];
    double a0 = 0.0, a1 = 0.0, a2 = 0.0, a3 = 0.0;
    for (int j = j0 + sub; j < j1; j += RPI) {
        float w = re.wD[j];
        uint2e v = *(const uint2e*)&re.msg[(size_t)j * H + c4 * 4];
        a0 += (double)(w * bfbits2f(v.x << 16));
        a1 += (double)(w * bfbits2f(v.x & 0xffff0000u));
        a2 += (double)(w * bfbits2f(v.y << 16));
        a3 += (double)(w * bfbits2f(v.y & 0xffff0000u));
    }
    #pragma unroll
    for (int ofs = 32; ofs >= HC; ofs >>= 1) {
        a0 += __shfl_down(a0, ofs); a1 += __shfl_down(a1, ofs);
        a2 += __shfl_down(a2, ofs); a3 += __shfl_down(a3, ofs);
    }
    if (lane < HC) {
        size_t o = (size_t)d * H + c4 * 4;
        float v0 = re.base[o] + (float)a0, v1 = re.base[o + 1] + (float)a1;
        float v2 = re.base[o + 2] + (float)a2, v3 = re.base[o + 3] + (float)a3;
        if (RELU) {
            v0 = fmaxf(v0, 0.f); v1 = fmaxf(v1, 0.f);
            v2 = fmaxf(v2, 0.f); v3 = fmaxf(v3, 0.f);
        }
        re.base[o] = v0; re.base[o + 1] = v1; re.base[o + 2] = v2; re.base[o + 3] = v3;
        if (RELU) {
            re.bfout[o] = f2bf(v0); re.bfout[o + 1] = f2bf(v1);
            re.bfout[o + 2] = f2bf(v2); re.bfout[o + 3] = f2bf(v3);
        }
    }
}

// column partial sums of x2_o -> part[block][32] (plain stores, deterministic)
__global__ void k_mean(const float* __restrict__ x2o, float* __restrict__ part) {
    __shared__ float s[256];
    int t = threadIdx.x; int hh = t & 31; int g = t >> 5;
    float acc = 0.f;
    for (int n = blockIdx.x * 8 + g; n < NN; n += gridDim.x * 8)
        acc += x2o[(size_t)n * 32 + hh];
    s[t] = acc;
    __syncthreads();
    if (t < 32) {
        float v = 0.f;
        for (int gg = 0; gg < 8; gg++) v += s[gg * 32 + t];
        part[blockIdx.x * 32 + t] = v;
    }
}

// deterministic final column sum: csum[c] = sum_b part[b][c] in fixed order
__global__ void k_csum(const float* __restrict__ part, float* __restrict__ csum) {
    int t = threadIdx.x;
    if (t < 32) {
        double a = 0.0;
        for (int b = 0; b < 256; b++) a += (double)part[b * 32 + t];
        csum[t] = (float)a;
    }
}

// c = sigmoid(csum/N); v = disc_W @ c; bilinear scores
__global__ void k_disc(const float* __restrict__ x2o, const float* __restrict__ x2a,
                       const float* __restrict__ x2aa, const float* __restrict__ csum,
                       const float* __restrict__ discW, const float* __restrict__ discb,
                       float* ret_os, float* ret_osa) {
    __shared__ float c[32], v[32];
    int t = threadIdx.x;
    if (t < 32) c[t] = 1.f / (1.f + expf(-csum[t] * (1.f / NN)));
    __syncthreads();
    if (t < 32) {
        float a = 0.f;
        for (int j = 0; j < 32; j++) a += discW[t * 32 + j] * c[j];
        v[t] = a;
    }
    __syncthreads();
    float db = discb[0];
    int n = blockIdx.x * 256 + t;
    if (n < NN) {
        float s1 = 0.f, s2 = 0.f, s3 = 0.f;
        for (int j = 0; j < 32; j++) {
            float vj = v[j];
            s1 += x2o[(size_t)n * 32 + j] * vj;
            s2 += x2a[(size_t)n * 32 + j] * vj;
            s3 += x2aa[(size_t)n * 32 + j] * vj;
        }
        ret_os[n * 2] = s1 + db;  ret_os[n * 2 + 1] = s2 + db;
        ret_osa[n * 2] = s1 + db; ret_osa[n * 2 + 1] = s3 + db;
    }
}

// pair classifier as MFMA GEMM (K padded to 512, N padded to 80)
__launch_bounds__(256, 2)
__global__ void k_clsg(const float* __restrict__ h1o, const float* __restrict__ x2o,
                       const float* __restrict__ feat, const float* __restrict__ attt,
                       const int* __restrict__ idx,
                       const unsigned short* __restrict__ cwt,
                       const float* __restrict__ clsb, float* __restrict__ log_out) {
    constexpr int LDK = CLS_CK + 8;
    __shared__ unsigned short As[CLS_BM][LDK];
    __shared__ unsigned short Bs[CLS_N][LDK];
    __shared__ int nd[2][CLS_BM];

    int tid = threadIdx.x;
    int p0 = blockIdx.x * CLS_BM;
    if (tid < CLS_BM) {
        nd[0][tid] = idx[p0 + tid];
        nd[1][tid] = idx[BB + p0 + tid];
    }
    float a0 = attt[0], a1 = attt[1];

    const int wave = tid >> 6;
    const int lane = tid & 63;
    const int q = lane >> 4;
    const int ln = lane & 15;
    constexpr int NT = CLS_N / 16;
    const int mbase = wave * 16;

    floatx4 acc[NT];
    #pragma unroll
    for (int nt = 0; nt < NT; nt++) acc[nt] = floatx4{0.f, 0.f, 0.f, 0.f};

    for (int ch = 0; ch < CLS_K / CLS_CK; ch++) {
        int kbase = ch * CLS_CK;
        __syncthreads();
        for (int c = tid; c < CLS_N * CLS_CK / 8; c += 256) {
            int row = c / (CLS_CK / 8), cc = c % (CLS_CK / 8);
            *(uint4*)&Bs[row][cc * 8] = *(const uint4*)&cwt[(size_t)row * CLS_K + kbase + cc * 8];
        }
        for (int c = tid; c < CLS_BM * CLS_CK / 4; c += 256) {
            int row = c / (CLS_CK / 4);
            int j4 = (c % (CLS_CK / 4)) * 4;
            int j = kbase + j4;
            float4 v = {0.f, 0.f, 0.f, 0.f};
            if (j < 448) {
                int hseg = j / 224, jj = j % 224;
                int node = nd[hseg][row];
                if (jj < 64) {
                    v = *(const float4*)&h1o[(size_t)node * 64 + jj];
                    v.x *= a0; v.y *= a0; v.z *= a0; v.w *= a0;
                } else if (jj < 96) {
                    v = *(const float4*)&x2o[(size_t)node * 32 + (jj - 64)];
                    v.x *= a1; v.y *= a1; v.z *= a1; v.w *= a1;
                } else {
                    v = *(const float4*)&feat[(size_t)node * 128 + (jj - 96)];
                }
            }
            uint2 pk;
            pk.x = (unsigned)f2bf(v.x) | ((unsigned)f2bf(v.y) << 16);
            pk.y = (unsigned)f2bf(v.z) | ((unsigned)f2bf(v.w) << 16);
            *(uint2*)&As[row][j4] = pk;
        }
        __syncthreads();
        #pragma unroll
        for (int ks = 0; ks < CLS_CK / 32; ks++) {
            int kk = ks * 32 + q * 8;
            short8 af = *(const short8*)&As[mbase + ln][kk];
            #pragma unroll
            for (int nt = 0; nt < NT; nt++) {
                short8 bf = *(const short8*)&Bs[nt * 16 + ln][kk];
                acc[nt] = __builtin_amdgcn_mfma_f32_16x16x32_bf16(af, bf, acc[nt], 0, 0, 0);
            }
        }
    }

    #pragma unroll
    for (int rr2 = 0; rr2 < 4; rr2++) {
        int i = mbase + q * 4 + rr2;
        int pair = p0 + i;
        #pragma unroll
        for (int nt = 0; nt < NT; nt++) {
            int col = nt * 16 + ln;
            if (col < RR)
                log_out[(size_t)pair * RR + col] = acc[nt][rr2] + clsb[col];
        }
    }
}

extern "C" void kernel_launch(void* const* d_in, const int* in_sizes, int n_in,
                              void* d_out, int out_size, void* d_ws, size_t ws_size,
                              hipStream_t stream) {
    const float* x_o   = (const float*)d_in[0];
    const float* x_a   = (const float*)d_in[1];
    const float* feat  = (const float*)d_in[2];
    const float* W1    = (const float*)d_in[3];
    const float* root1 = (const float*)d_in[4];
    const float* b1    = (const float*)d_in[5];
    const float* W2    = (const float*)d_in[6];
    const float* root2 = (const float*)d_in[7];
    const float* b2    = (const float*)d_in[8];
    const float* attt  = (const float*)d_in[9];
    const float* discW = (const float*)d_in[10];
    const float* discb = (const float*)d_in[11];
    const float* clsW  = (const float*)d_in[12];
    const float* clsb  = (const float*)d_in[13];
    const int* ei      = (const int*)d_in[14];
    const int* et0     = (const int*)d_in[15];
    const int* et1     = (const int*)d_in[16];
    const int* idx     = (const int*)d_in[17];

    char* ws = (char*)d_ws;
    float* csum = (float*)(ws + OFF_CSUM);
    int* cntD  = (int*)(ws + OFF_CNTD);
    int* dstOff = (int*)(ws + OFF_DSTOFF);
    int* bh0   = (int*)(ws + OFF_BH0);
    int* bh1   = (int*)(ws + OFF_BH1);
    int* bb0   = (int*)(ws + OFF_BB0);
    int* bb1   = (int*)(ws + OFF_BB1);
    int* hT    = (int*)(ws + OFF_HT);
    int* offB0 = (int*)(ws + OFF_OFFB0);
    int* offB1 = (int*)(ws + OFF_OFFB1);
    int* tilB0 = (int*)(ws + OFF_TILB0);
    int* tilT0 = (int*)(ws + OFF_TILT0);
    int* tilB1 = (int*)(ws + OFF_TILB1);
    int* tilT1 = (int*)(ws + OFF_TILT1);
    int* slotE = (int*)(ws + OFF_SLOT);
    int* posD  = (int*)(ws + OFF_POSD);
    unsigned int* rdP = (unsigned int*)(ws + OFF_RDP);
    float* wD0 = (float*)(ws + OFF_WD0);
    float* wD1 = (float*)(ws + OFF_WD1);
    unsigned int* perm0 = (unsigned int*)(ws + OFF_PERM0);
    unsigned int* perm1 = (unsigned int*)(ws + OFF_PERM1);
    unsigned short* xob = (unsigned short*)(ws + OFF_XOB);
    unsigned short* xab = (unsigned short*)(ws + OFF_XAB);
    float* h1o  = (float*)(ws + OFF_H1);
    float* h1a  = h1o + (size_t)NN * HH1;
    float* h1aa = h1a + (size_t)NN * HH1;
    unsigned short* h1bo  = (unsigned short*)(ws + OFF_H1B);
    unsigned short* h1ba  = h1bo + (size_t)NN * HH1;
    unsigned short* h1baa = h1ba + (size_t)NN * HH1;
    float* x2a  = (float*)(ws + OFF_X2A);
    float* x2aa = (float*)(ws + OFF_X2AA);
    unsigned short* w1t = (unsigned short*)(ws + OFF_W1BT);
    unsigned short* w2t = (unsigned short*)(ws + OFF_W2BT);
    unsigned short* r1t = (unsigned short*)(ws + OFF_R1T);
    unsigned short* r2t = (unsigned short*)(ws + OFF_R2T);
    unsigned short* cwt = (unsigned short*)(ws + OFF_CWT);
    float* part = (float*)(ws + OFF_PART);
    unsigned short* msg = (unsigned short*)(ws + OFF_MSG);

    float* out = (float*)d_out;
    float* log_out = out + O_LOG;
    float* ret_os  = out + O_ROS;
    float* ret_osa = out + O_ROSA;
    float* x2o     = out + O_X2O;

    // pairing needs 2 msg buffers; fall back to 3 serial singles otherwise
    size_t availMsg = ws_size > OFF_MSG ? ws_size - OFF_MSG : MSG_B1;
    bool pair1 = availMsg >= 2 * MSG_B1;
    bool pair2 = availMsg >= 2 * MSG_B2;

    // 1) zero control block (csum + cntD) — ~80 KB
    hipMemsetAsync(ws, 0, ZERO_BYTES, stream);

    // 2) preprocessing: (octile,relation) bucket sort with packed metadata
    k_hist<<<GRID_PRE, 256, 0, stream>>>(ei, et0, et1, cntD, slotE, bh0, bh1,
                                         x_o, x_a, W1, W2, root1, root2, clsW,
                                         xob, xab, w1t, w2t, r1t, r2t, cwt);
    k_scanD<<<1, 256, 0, stream>>>(cntD, dstOff);
    k_post<<<2500, 256, 0, stream>>>(ei, et0, et1, dstOff, slotE, posD, rdP);
    k_scanB1<<<(2 * NB2 + 3) / 4, 256, 0, stream>>>(bh0, bh1, bb0, bb1, hT);
    k_scanB2<<<1, 256, 0, stream>>>(hT, offB0, offB1,
                                    tilB0, tilT0, tilB1, tilT1);
    k_fillB<<<NBH, 256, 0, stream>>>(ei, et0, et1, posD, offB0, offB1, bb0, bb1,
                                     perm0, perm1);
    k_wts<<<NN / 4, 256, 0, stream>>>(dstOff, rdP, wD0, wD1);

    // 3) layer 1: root GEMM + paired (enc0,enc1) edge GEMM + enc2 single
    {
        dim3 gb(NBT, 3);
        k_bgemm<FIN1, HH1><<<gb, 256, 0, stream>>>(xob, xab, xob, r1t, b1,
                                                   h1o, h1a, h1aa);
        unsigned short* msg0 = msg;
        unsigned short* msg1 = msg + (size_t)EE * HH1;
        if (pair1) {
            k_gemm2<FIN1, HH1><<<MAXT2, 512, 0, stream>>>(xob, xab, msg0, msg1,
                                                          perm0, offB0, tilB0, tilT0, w1t);
            RedArgs ra{};
            ra.e[0] = RedEnc{msg0, wD0, h1o, h1bo};
            ra.e[1] = RedEnc{msg1, wD0, h1a, h1ba};
            k_reduce<HH1, true><<<dim3(NN / 4, 2), 256, 0, stream>>>(ra, dstOff);
            k_gemm<FIN1, HH1><<<MAXT2, 512, 0, stream>>>(xob, msg0, perm1, offB1,
                                                         tilB1, tilT1, w1t);
            RedArgs rb{};
            rb.e[0] = RedEnc{msg0, wD1, h1aa, h1baa};
            k_reduce<HH1, true><<<dim3(NN / 4, 1), 256, 0, stream>>>(rb, dstOff);
        } else {
            const unsigned short* Xs[3] = {xob, xab, xob};
            float* Os[3] = {h1o, h1a, h1aa};
            unsigned short* Obs[3] = {h1bo, h1ba, h1baa};
            for (int enc = 0; enc < 3; enc++) {
                k_gemm<FIN1, HH1><<<MAXT2, 512, 0, stream>>>(
                    Xs[enc], msg0,
                    enc == 2 ? perm1 : perm0, enc == 2 ? offB1 : offB0,
                    enc == 2 ? tilB1 : tilB0, enc == 2 ? tilT1 : tilT0, w1t);
                RedArgs ra{};
                ra.e[0] = RedEnc{msg0, enc == 2 ? wD1 : wD0, Os[enc], Obs[enc]};
                k_reduce<HH1, true><<<dim3(NN / 4, 1), 256, 0, stream>>>(ra, dstOff);
            }
        }
    }

    // 4) layer 2: root GEMM + paired (enc0,enc1) edge GEMM + enc2 single
    {
        dim3 gb(NBT, 3);
        k_bgemm<HH1, HH2><<<gb, 256, 0, stream>>>(h1bo, h1ba, h1baa, r2t, b2,
                                                  x2o, x2a, x2aa);
        unsigned short* msg0 = msg;
        unsigned short* msg1 = msg + (size_t)EE * HH2;
        if (pair2) {
            k_gemm2<HH1, HH2><<<MAXT2, 512, 0, stream>>>(h1bo, h1ba, msg0, msg1,
                                                         perm0, offB0, tilB0, tilT0, w2t);
            RedArgs ra{};
            ra.e[0] = RedEnc{msg0, wD0, x2o, nullptr};
            ra.e[1] = RedEnc{msg1, wD0, x2a, nullptr};
            k_reduce<HH2, false><<<dim3(NN / 4, 2), 256, 0, stream>>>(ra, dstOff);
            k_gemm<HH1, HH2><<<MAXT2, 512, 0, stream>>>(h1baa, msg0, perm1, offB1,
                                                        tilB1, tilT1, w2t);
            RedArgs rb{};
            rb.e[0] = RedEnc{msg0, wD1, x2aa, nullptr};
            k_reduce<HH2, false><<<dim3(NN / 4, 1), 256, 0, stream>>>(rb, dstOff);
        } else {
            const unsigned short* Xs[3] = {h1bo, h1ba, h1baa};
            float* Os[3] = {x2o, x2a, x2aa};
            for (int enc = 0; enc < 3; enc++) {
                k_gemm<HH1, HH2><<<MAXT2, 512, 0, stream>>>(
                    Xs[enc], msg0,
                    enc == 2 ? perm1 : perm0, enc == 2 ? offB1 : offB0,
                    enc == 2 ? tilB1 : tilB0, enc == 2 ? tilT1 : tilT0, w2t);
                RedArgs ra{};
                ra.e[0] = RedEnc{msg0, enc == 2 ? wD1 : wD0, Os[enc], nullptr};
                k_reduce<HH2, false><<<dim3(NN / 4, 1), 256, 0, stream>>>(ra, dstOff);
            }
        }
    }

    // 5) readout + discriminator + classifier
    k_mean<<<256, 256, 0, stream>>>(x2o, part);
    k_csum<<<1, 64, 0, stream>>>(part, csum);
    k_disc<<<(NN + 255) / 256, 256, 0, stream>>>(x2o, x2a, x2aa, csum, discW, discb,
                                                 ret_os, ret_osa);
    k_clsg<<<BB / CLS_BM, 256, 0, stream>>>(h1o, x2o, feat, attt, idx, cwt, clsb, log_out);
}

// Round 9
// 555.798 us; speedup vs baseline: 1.0853x; 1.0853x over previous
//
#include <hip/hip_runtime.h>
#include <hip/hip_bf16.h>

// ---------------- problem constants ----------------
#define NN 20000      // nodes
#define EE 640000     // edges
#define RR 65         // relations
#define FIN1 128      // input feat
#define HH1 64        // hidden1
#define HH2 32        // hidden2
#define BB 8192       // pairs

constexpr int BM = 128;                 // node-tile rows (root GEMM)
constexpr int GBM = 256;                // edge-tile rows per gather-GEMM block
constexpr int NBH = 256;                // histogram/placement blocks
constexpr int GRID_PRE = 2048;          // k_hist launch grid (occupancy for conversions)
constexpr int EPB = EE / NBH;           // 2500 edges per block
constexpr int NBT = (NN + BM - 1) / BM; // 157 node tiles
constexpr int NOCT = 8;                 // src octiles (nodes per octile = 2500)
constexpr int NPO = NN / NOCT;          // 2500
constexpr int NB2 = NOCT * RR;          // 520 sort buckets (octile-major, relation inner)
constexpr int MAXT2 = EE / GBM + NB2;   // 3020 tile upper bound (256-edge tiles)

// classifier GEMM geometry (E[8192x448] @ clsW[448x65], padded)
constexpr int CLS_K  = 512;
constexpr int CLS_N  = 80;
constexpr int CLS_CK = 128;
constexpr int CLS_BM = 64;

typedef __attribute__((ext_vector_type(8))) short short8;   // 8 bf16 MFMA frag
typedef __attribute__((ext_vector_type(4))) float floatx4;  // 4 fp32 acc
typedef __attribute__((ext_vector_type(4))) unsigned int uint4e;  // 16B vector
typedef __attribute__((ext_vector_type(2))) unsigned int uint2e;  // 8B vector

// ---------------- workspace layout (bytes) ----------------
constexpr size_t aln(size_t x) { return (x + 255) & ~(size_t)255; }

constexpr size_t OFF_CSUM  = 0;                        // 32 f
constexpr size_t OFF_CNTD  = aln(OFF_CSUM + 32 * 4);  // NN int (dst degree)
constexpr size_t ZERO_BYTES = OFF_CNTD + (size_t)NN * 4;   // memset [0, ZERO_BYTES)
constexpr size_t OFF_DSTOFF = aln(ZERO_BYTES);         // NN+1 int
constexpr size_t OFF_BH0   = aln(OFF_DSTOFF + ((size_t)NN + 1) * 4); // NBH*NB2
constexpr size_t OFF_BH1   = OFF_BH0 + (size_t)NBH * NB2 * 4;
constexpr size_t OFF_BB0   = OFF_BH1 + (size_t)NBH * NB2 * 4;
constexpr size_t OFF_BB1   = OFF_BB0 + (size_t)NBH * NB2 * 4;
constexpr size_t OFF_HT    = aln(OFF_BB1 + (size_t)NBH * NB2 * 4);   // 2*NB2 int totals
constexpr size_t OFF_OFFB0 = aln(OFF_HT + (size_t)2 * NB2 * 4);      // NB2+1 int
constexpr size_t OFF_OFFB1 = OFF_OFFB0 + (NB2 + 1) * 4;
constexpr size_t OFF_TILB0 = aln(OFF_OFFB1 + (NB2 + 1) * 4);  // MAXT2 int
constexpr size_t OFF_TILT0 = OFF_TILB0 + (size_t)MAXT2 * 4;
constexpr size_t OFF_TILB1 = OFF_TILT0 + (size_t)MAXT2 * 4;
constexpr size_t OFF_TILT1 = OFF_TILB1 + (size_t)MAXT2 * 4;
constexpr size_t OFF_SLOT  = aln(OFF_TILT1 + (size_t)MAXT2 * 4);  // E int
constexpr size_t OFF_POSD  = OFF_SLOT + (size_t)EE * 4;           // E int (e -> dst pos)
constexpr size_t OFF_RDP   = OFF_POSD + (size_t)EE * 4;           // E uint (pos -> r0|r1<<16)
constexpr size_t OFF_WD0   = OFF_RDP + (size_t)EE * 4;            // E float (pos-space weights)
constexpr size_t OFF_WD1   = OFF_WD0 + (size_t)EE * 4;
constexpr size_t OFF_PERM0 = OFF_WD1 + (size_t)EE * 4;            // E uint (srcLocal<<20|pos)
constexpr size_t OFF_PERM1 = OFF_PERM0 + (size_t)EE * 4;
constexpr size_t OFF_XOB   = aln(OFF_PERM1 + (size_t)EE * 4);     // N*F bf16
constexpr size_t OFF_XAB   = OFF_XOB + (size_t)NN * FIN1 * 2;
constexpr size_t OFF_H1    = aln(OFF_XAB + (size_t)NN * FIN1 * 2); // 3 * N*64 f
constexpr size_t OFF_H1B   = OFF_H1 + (size_t)3 * NN * HH1 * 4;    // 3 * N*64 bf16
constexpr size_t OFF_X2A   = OFF_H1B + (size_t)3 * NN * HH1 * 2;   // N*32 f
constexpr size_t OFF_X2AA  = OFF_X2A + (size_t)NN * HH2 * 4;
constexpr size_t OFF_W1BT  = OFF_X2AA + (size_t)NN * HH2 * 4;      // R*64*128 bf16
constexpr size_t OFF_W2BT  = OFF_W1BT + (size_t)RR * HH1 * FIN1 * 2;
constexpr size_t OFF_R1T   = OFF_W2BT + (size_t)RR * HH2 * HH1 * 2;
constexpr size_t OFF_R2T   = OFF_R1T + (size_t)HH1 * FIN1 * 2;
constexpr size_t OFF_CWT   = OFF_R2T + (size_t)HH2 * HH1 * 2;
constexpr size_t OFF_PART  = aln(OFF_CWT + (size_t)CLS_N * CLS_K * 2); // 256*32 f partials
constexpr size_t OFF_MSG   = aln(OFF_PART + (size_t)256 * 32 * 4);     // msg buffers (1..3)
constexpr size_t MSG_B1    = (size_t)EE * HH1 * 2;   // one layer-1 msg buffer
constexpr size_t MSG_B2    = (size_t)EE * HH2 * 2;   // one layer-2 msg buffer
constexpr size_t WS_END    = OFF_MSG + MSG_B1;       // minimum required (1 buffer)

// output offsets (floats)
constexpr size_t O_LOG  = 0;
constexpr size_t O_ROS  = (size_t)BB * RR;
constexpr size_t O_ROSA = O_ROS + (size_t)NN * 2;
constexpr size_t O_X2O  = O_ROSA + (size_t)NN * 2;

__device__ inline unsigned short f2bf(float f) {
    __hip_bfloat16 h = __float2bfloat16(f);
    return *reinterpret_cast<unsigned short*>(&h);
}
__device__ inline float bfbits2f(unsigned int hi_bits) {
    return __uint_as_float(hi_bits);
}

// per-enc pointer bundles for merged launches
struct GemmEnc {
    const unsigned short* X;
    unsigned short* msg;
    const unsigned int* perm;
    const int* offB;
    const int* tilB;
    const int* tilT;
};
struct GemmArgs { GemmEnc e[3]; };

struct RedEnc {
    const unsigned short* msg;
    const float* wD;
    float* base;
    unsigned short* bfout;
};
struct RedArgs { RedEnc e[3]; };

// ---------------- preprocessing ----------------
// blocks < NBH: per-block 520-bin (octile,relation) histograms via LDS,
// per-dst degree + slot. ALL blocks: vectorized streaming bf16 conversions.
__global__ void k_hist(const int* __restrict__ ei, const int* __restrict__ et0,
                       const int* __restrict__ et1,
                       int* cntD, int* __restrict__ slotE,
                       int* __restrict__ bh0, int* __restrict__ bh1,
                       const float* __restrict__ x_o, const float* __restrict__ x_a,
                       const float* __restrict__ W1, const float* __restrict__ W2,
                       const float* __restrict__ root1, const float* __restrict__ root2,
                       const float* __restrict__ clsW,
                       unsigned short* xob, unsigned short* xab,
                       unsigned short* w1t, unsigned short* w2t,
                       unsigned short* r1t, unsigned short* r2t,
                       unsigned short* cwt) {
    __shared__ int lh0[NB2], lh1[NB2];
    int t = threadIdx.x;
    if (blockIdx.x < NBH) {
        for (int p = t; p < NB2; p += 256) { lh0[p] = 0; lh1[p] = 0; }
        __syncthreads();
        int base = blockIdx.x * EPB;
        for (int i = t; i < EPB; i += 256) {
            int e = base + i;
            int oct = ei[e] / NPO;
            atomicAdd(&lh0[oct * RR + et0[e]], 1);
            atomicAdd(&lh1[oct * RR + et1[e]], 1);
            slotE[e] = atomicAdd(&cntD[ei[EE + e]], 1);
        }
        __syncthreads();
        for (int p = t; p < NB2; p += 256) {
            bh0[blockIdx.x * NB2 + p] = lh0[p];
            bh1[blockIdx.x * NB2 + p] = lh1[p];
        }
    }
    // streaming conversions (grid-stride, vectorized 4-wide)
    int stride = gridDim.x * 256;
    int i0 = blockIdx.x * 256 + t;
    const int NX4 = NN * FIN1 / 4;
    const float4* xo4 = (const float4*)x_o;
    const float4* xa4 = (const float4*)x_a;
    for (int i = i0; i < NX4; i += stride) {
        float4 a = xo4[i], b = xa4[i];
        uint2 pa, pb;
        pa.x = (unsigned)f2bf(a.x) | ((unsigned)f2bf(a.y) << 16);
        pa.y = (unsigned)f2bf(a.z) | ((unsigned)f2bf(a.w) << 16);
        pb.x = (unsigned)f2bf(b.x) | ((unsigned)f2bf(b.y) << 16);
        pb.y = (unsigned)f2bf(b.z) | ((unsigned)f2bf(b.w) << 16);
        ((uint2*)xob)[i] = pa;
        ((uint2*)xab)[i] = pb;
    }
    const int NW1_4 = RR * HH1 * FIN1 / 4;
    for (int i4 = i0; i4 < NW1_4; i4 += stride) {
        int i = i4 * 4;
        int k = i % FIN1; int rh = i / FIN1; int hh = rh % HH1; int r = rh / HH1;
        const float* s = &W1[((size_t)r * FIN1 + k) * HH1 + hh];
        uint2 pk;
        pk.x = (unsigned)f2bf(s[0]) | ((unsigned)f2bf(s[HH1]) << 16);
        pk.y = (unsigned)f2bf(s[2 * HH1]) | ((unsigned)f2bf(s[3 * HH1]) << 16);
        ((uint2*)w1t)[i4] = pk;
    }
    const int NW2_4 = RR * HH2 * HH1 / 4;
    for (int i4 = i0; i4 < NW2_4; i4 += stride) {
        int i = i4 * 4;
        int k = i % HH1; int rh = i / HH1; int hh = rh % HH2; int r = rh / HH2;
        const float* s = &W2[((size_t)r * HH1 + k) * HH2 + hh];
        uint2 pk;
        pk.x = (unsigned)f2bf(s[0]) | ((unsigned)f2bf(s[HH2]) << 16);
        pk.y = (unsigned)f2bf(s[2 * HH2]) | ((unsigned)f2bf(s[3 * HH2]) << 16);
        ((uint2*)w2t)[i4] = pk;
    }
    const int NR1_4 = HH1 * FIN1 / 4;
    for (int i4 = i0; i4 < NR1_4; i4 += stride) {
        int i = i4 * 4;
        int k = i % FIN1; int hh = i / FIN1;
        const float* s = &root1[(size_t)k * HH1 + hh];
        uint2 pk;
        pk.x = (unsigned)f2bf(s[0]) | ((unsigned)f2bf(s[HH1]) << 16);
        pk.y = (unsigned)f2bf(s[2 * HH1]) | ((unsigned)f2bf(s[3 * HH1]) << 16);
        ((uint2*)r1t)[i4] = pk;
    }
    const int NR2_4 = HH2 * HH1 / 4;
    for (int i4 = i0; i4 < NR2_4; i4 += stride) {
        int i = i4 * 4;
        int k = i % HH1; int hh = i / HH1;
        const float* s = &root2[(size_t)k * HH2 + hh];
        uint2 pk;
        pk.x = (unsigned)f2bf(s[0]) | ((unsigned)f2bf(s[HH2]) << 16);
        pk.y = (unsigned)f2bf(s[2 * HH2]) | ((unsigned)f2bf(s[3 * HH2]) << 16);
        ((uint2*)r2t)[i4] = pk;
    }
    const int NCW_4 = CLS_N * CLS_K / 4;
    for (int i4 = i0; i4 < NCW_4; i4 += stride) {
        int i = i4 * 4;
        int k = i % CLS_K; int n = i / CLS_K;
        uint2 pk = {0u, 0u};
        if (n < RR && k < 448) {
            const float* s = &clsW[(size_t)k * RR + n];
            pk.x = (unsigned)f2bf(s[0]) | ((unsigned)f2bf(s[RR]) << 16);
            pk.y = (unsigned)f2bf(s[2 * RR]) | ((unsigned)f2bf(s[3 * RR]) << 16);
        }
        ((uint2*)cwt)[i4] = pk;
    }
}

// exclusive scan of per-dst degrees -> dstOff[NN+1] (single block)
__global__ void k_scanD(const int* __restrict__ cntD, int* __restrict__ dstOff) {
    __shared__ int s[256];
    int t = threadIdx.x;
    constexpr int PER = (NN + 255) / 256;
    int lo = t * PER, hi = min(NN, lo + PER);
    int sum = 0;
    for (int i = lo; i < hi; i++) sum += cntD[i];
    s[t] = sum;
    __syncthreads();
    for (int ofs = 1; ofs < 256; ofs <<= 1) {
        int v = 0;
        if (t >= ofs) v = s[t - ofs];
        __syncthreads();
        if (t >= ofs) s[t] += v;
        __syncthreads();
    }
    int run = s[t] - sum;
    for (int i = lo; i < hi; i++) { dstOff[i] = run; run += cntD[i]; }
    if (t == 255) dstOff[NN] = run;
}

// posD (sequential write) + rdP (the single scattered-write array)
__global__ void k_post(const int* __restrict__ ei, const int* __restrict__ et0,
                       const int* __restrict__ et1, const int* __restrict__ dstOff,
                       const int* __restrict__ slotE,
                       int* __restrict__ posD, unsigned int* __restrict__ rdP) {
    int e = blockIdx.x * 256 + threadIdx.x;
    if (e < EE) {
        int d = ei[EE + e];
        int pos = dstOff[d] + slotE[e];
        posD[e] = pos;
        rdP[pos] = (unsigned)et0[e] | ((unsigned)et1[e] << 16);
    }
}

// phase 1: per-bucket exclusive prefix over the 256 histogram blocks.
__global__ void k_scanB1(const int* __restrict__ bh0, const int* __restrict__ bh1,
                         int* __restrict__ bb0, int* __restrict__ bb1,
                         int* __restrict__ hT) {
    int w = (blockIdx.x * 256 + threadIdx.x) >> 6;
    int lane = threadIdx.x & 63;
    if (w >= 2 * NB2) return;
    int s = w / NB2, k = w % NB2;
    const int* bh = s ? bh1 : bh0;
    int* bb = s ? bb1 : bb0;
    int v[4];
    #pragma unroll
    for (int i = 0; i < 4; i++) v[i] = bh[(size_t)(lane * 4 + i) * NB2 + k];
    int ls = v[0] + v[1] + v[2] + v[3];
    int inc = ls;
    #pragma unroll
    for (int ofs = 1; ofs < 64; ofs <<= 1) {
        int o = __shfl_up(inc, ofs);
        if (lane >= ofs) inc += o;
    }
    int run = inc - ls;   // exclusive base for this lane
    #pragma unroll
    for (int i = 0; i < 4; i++) {
        bb[(size_t)(lane * 4 + i) * NB2 + k] = run;
        run += v[i];
    }
    if (lane == 63) hT[s * NB2 + k] = run;  // column total
}

// phase 2 (single block): bucket offsets + tile tables from the 1040 totals.
__global__ void k_scanB2(const int* __restrict__ hT,
                         int* offB0, int* offB1,
                         int* tilB0, int* tilT0, int* tilB1, int* tilT1) {
    __shared__ int h[2][NB2];
    __shared__ int o[2][NB2 + 1];
    __shared__ int to[2][NB2 + 1];
    __shared__ int csumE[2][8], csumT[2][8];
    int t = threadIdx.x;
    for (int p = t; p < 2 * NB2; p += 256) h[p / NB2][p % NB2] = hT[p];
    __syncthreads();
    if (t < 16) {
        int s = t / 8, c = t % 8;
        int runE = 0, runT = 0;
        for (int k = c * RR; k < (c + 1) * RR; k++) {
            o[s][k] = runE;  runE += h[s][k];
            to[s][k] = runT; runT += (h[s][k] + GBM - 1) / GBM;
        }
        csumE[s][c] = runE; csumT[s][c] = runT;
    }
    __syncthreads();
    if (t < 2) {
        int runE = 0, runT = 0;
        for (int c = 0; c < 8; c++) {
            int e = csumE[t][c], tt = csumT[t][c];
            csumE[t][c] = runE; csumT[t][c] = runT;
            runE += e; runT += tt;
        }
        o[t][NB2] = runE; to[t][NB2] = runT;
    }
    __syncthreads();
    if (t < 16) {
        int s = t / 8, c = t % 8;
        for (int k = c * RR; k < (c + 1) * RR; k++) {
            o[s][k] += csumE[s][c];
            to[s][k] += csumT[s][c];
        }
    }
    __syncthreads();
    for (int p = t; p <= NB2; p += 256) { offB0[p] = o[0][p]; offB1[p] = o[1][p]; }
    for (int i = t; i < MAXT2; i += 256) {
        #pragma unroll
        for (int s = 0; s < 2; s++) {
            int total = to[s][NB2];
            int bkt = -1, ti = 0;
            if (i < total) {
                int lo = 0, hi = NB2;
                while (hi - lo > 1) { int mid = (lo + hi) >> 1; if (to[s][mid] <= i) lo = mid; else hi = mid; }
                bkt = lo;
                ti = i - to[s][lo];
            }
            if (s == 0) { tilB0[i] = bkt; tilT0[i] = ti; }
            else        { tilB1[i] = bkt; tilT1[i] = ti; }
        }
    }
}

// bucket-sorted perm placement with deterministic bases.
__global__ void k_fillB(const int* __restrict__ ei, const int* __restrict__ et0,
                        const int* __restrict__ et1, const int* __restrict__ posD,
                        const int* __restrict__ offB0, const int* __restrict__ offB1,
                        const int* __restrict__ bb0, const int* __restrict__ bb1,
                        unsigned int* perm0, unsigned int* perm1) {
    __shared__ int lc[2][NB2];
    __shared__ int lb[2][NB2];
    int t = threadIdx.x;
    for (int p = t; p < NB2; p += 256) {
        lc[0][p] = 0; lc[1][p] = 0;
        lb[0][p] = offB0[p] + bb0[blockIdx.x * NB2 + p];
        lb[1][p] = offB1[p] + bb1[blockIdx.x * NB2 + p];
    }
    __syncthreads();
    int base = blockIdx.x * EPB;
    for (int i = t; i < EPB; i += 256) {
        int e = base + i;
        int src = ei[e];                 // sequential read
        int pos = posD[e];               // sequential read
        int oct = src / NPO;
        unsigned int packed = ((unsigned)(src - oct * NPO) << 20) | (unsigned)pos;
        int k0 = oct * RR + et0[e];
        int k1 = oct * RR + et1[e];
        int p0 = atomicAdd(&lc[0][k0], 1);
        int p1 = atomicAdd(&lc[1][k1], 1);
        perm0[lb[0][k0] + p0] = packed;
        perm1[lb[1][k1] + p1] = packed;
    }
}

// per-(relation,dst) mean weights inside each dst segment -> pos-space arrays
__global__ void k_wts(const int* __restrict__ dstOff, const unsigned int* __restrict__ rdP,
                      float* __restrict__ wD0, float* __restrict__ wD1) {
    constexpr int CAP = 96;
    __shared__ unsigned int ld[4][CAP];
    int wave = threadIdx.x >> 6;
    int lane = threadIdx.x & 63;
    int d = blockIdx.x * 4 + wave;
    int j0 = 0, deg = 0;
    if (d < NN) { j0 = dstOff[d]; deg = dstOff[d + 1] - j0; }
    for (int j = lane; j < deg && j < CAP; j += 64) ld[wave][j] = rdP[j0 + j];
    __syncthreads();
    for (int j = lane; j < deg; j += 64) {
        unsigned int my = (j < CAP) ? ld[wave][j] : rdP[j0 + j];
        unsigned int m0 = my & 0xffffu, m1 = my >> 16;
        int c0 = 0, c1 = 0;
        for (int k = 0; k < deg; k++) {
            unsigned int p = (k < CAP) ? ld[wave][k] : rdP[j0 + k];
            c0 += ((p & 0xffffu) == m0);
            c1 += ((p >> 16) == m1);
        }
        wD0[j0 + j] = 1.0f / (float)c0;
        wD1[j0 + j] = 1.0f / (float)c1;
    }
}

// root-term GEMM via MFMA: O[n,h] = Xb[n,:] @ rootT[h,:] + bias[h]  (fp32 out)
template <int FIN, int HOUT>
__launch_bounds__(256, 3)
__global__ void k_bgemm(const unsigned short* __restrict__ X0,
                        const unsigned short* __restrict__ X1,
                        const unsigned short* __restrict__ X2,
                        const unsigned short* __restrict__ rootT,
                        const float* __restrict__ bias,
                        float* O0, float* O1, float* O2) {
    const int enc = blockIdx.y;
    const unsigned short* X = enc == 0 ? X0 : enc == 1 ? X1 : X2;
    float* O = enc == 0 ? O0 : enc == 1 ? O1 : O2;
    int n0 = blockIdx.x * BM;
    int mcount = min(BM, NN - n0);

    constexpr int LDK = FIN + 8;
    __shared__ unsigned short As[BM][LDK];
    __shared__ unsigned short Bs[HOUT][LDK];

    int tid = threadIdx.x;
    {
        constexpr int CHB = HOUT * FIN / 8;
        for (int c = tid; c < CHB; c += 256) {
            int row = c / (FIN / 8), cc = c % (FIN / 8);
            *(uint4*)&Bs[row][cc * 8] = *(const uint4*)&rootT[row * FIN + cc * 8];
        }
    }
    {
        constexpr int CHA = BM * FIN / 8;
        for (int c = tid; c < CHA; c += 256) {
            int row = c / (FIN / 8), cc = c % (FIN / 8);
            uint4 v = {0u, 0u, 0u, 0u};
            if (row < mcount) v = *(const uint4*)&X[(size_t)(n0 + row) * FIN + cc * 8];
            *(uint4*)&As[row][cc * 8] = v;
        }
    }
    __syncthreads();

    const int wave = tid >> 6;
    const int lane = tid & 63;
    const int q = lane >> 4;
    const int ln = lane & 15;
    constexpr int NT = HOUT / 16;
    constexpr int KS = FIN / 32;
    const int mbase = wave * 32;

    floatx4 acc[2][NT];
    #pragma unroll
    for (int a = 0; a < 2; a++)
        #pragma unroll
        for (int nt = 0; nt < NT; nt++) acc[a][nt] = floatx4{0.f, 0.f, 0.f, 0.f};

    for (int ks = 0; ks < KS; ks++) {
        int kk = ks * 32 + q * 8;
        short8 af0 = *(const short8*)&As[mbase + ln][kk];
        short8 af1 = *(const short8*)&As[mbase + 16 + ln][kk];
        #pragma unroll
        for (int nt = 0; nt < NT; nt++) {
            short8 bf = *(const short8*)&Bs[nt * 16 + ln][kk];
            acc[0][nt] = __builtin_amdgcn_mfma_f32_16x16x32_bf16(af0, bf, acc[0][nt], 0, 0, 0);
            acc[1][nt] = __builtin_amdgcn_mfma_f32_16x16x32_bf16(af1, bf, acc[1][nt], 0, 0, 0);
        }
    }

    #pragma unroll
    for (int mt = 0; mt < 2; mt++) {
        #pragma unroll
        for (int rr2 = 0; rr2 < 4; rr2++) {
            int i = mbase + mt * 16 + q * 4 + rr2;
            int n = n0 + i;
            if (i < mcount) {
                #pragma unroll
                for (int nt = 0; nt < NT; nt++)
                    O[(size_t)n * HOUT + nt * 16 + ln] = acc[mt][nt][rr2] + bias[nt * 16 + ln];
            }
        }
    }
}

// bucket-grouped gather-GEMM with MFMA — R7 operand plan (A fragments to
// registers, B staged in LDS) extended to GBM=256-edge tiles: each of the
// 8 waves owns TWO 16-row m-tiles. Unlike R8's pairing (which doubled the
// per-block cache footprint: 2 X arrays + 2 write streams -> FETCH 2x,
// WRITE 1.75x), this keeps ONE X array and ONE msg stream while halving
// perm/B staging per edge and doubling MFMA per B ds_read (32 MFMA vs
// 16 ds_read_b128 per wave — the LDS reads were the critical path at
// GBM=128). Accumulation order per output unchanged -> bitwise-identical.
template <int FIN, int HOUT>
__launch_bounds__(512, 8)
__global__ void k_gemm(GemmArgs ga, const unsigned short* __restrict__ WT) {
    const GemmEnc ge = ga.e[blockIdx.y];
    int b = blockIdx.x;
    int bkt = ge.tilB[b];
    if (bkt < 0) return;
    int r = bkt % RR;
    int srcBase = (bkt / RR) * NPO;
    int t = ge.tilT[b];
    int ebase = ge.offB[bkt] + t * GBM;
    int mcount = min(GBM, ge.offB[bkt + 1] - ebase);

    constexpr int LDK = FIN + 8;
    constexpr int LDM = HOUT + 8;
    constexpr int BSZ = HOUT * LDK;      // Bs region (shorts)
    constexpr int MSZ = GBM * LDM;       // epilogue msg staging (shorts)
    constexpr int USZ = BSZ > MSZ ? BSZ : MSZ;
    __shared__ unsigned short Us[USZ];   // Bs during K-loop, Ms in epilogue
    __shared__ int Sr[GBM];
    __shared__ int Pd[GBM];

    int tid = threadIdx.x;
    if (tid < GBM) {
        if (tid < mcount) {
            unsigned int p = ge.perm[ebase + tid];   // sequential
            Sr[tid] = srcBase + (int)(p >> 20);
            Pd[tid] = (int)(p & 0xFFFFFu);
        } else { Sr[tid] = -1; Pd[tid] = 0; }
    }
    {
        const unsigned short* Wr = WT + (size_t)r * HOUT * FIN;
        constexpr int CHB = HOUT * FIN / 8;
        for (int c = tid; c < CHB; c += 512) {
            int row = c / (FIN / 8), cc = c % (FIN / 8);
            *(uint4*)&Us[row * LDK + cc * 8] = *(const uint4*)&Wr[row * FIN + cc * 8];
        }
    }
    __syncthreads();

    const int wave = tid >> 6;       // 0..7
    const int lane = tid & 63;
    const int q = lane >> 4;
    const int ln = lane & 15;
    constexpr int NT = HOUT / 16;
    constexpr int KS = FIN / 32;
    const int mbase = wave * 32;     // two 16-row m-tiles per wave

    int s0 = Sr[mbase + ln];
    int s1 = Sr[mbase + 16 + ln];
    short8 A0[KS], A1[KS];
    #pragma unroll
    for (int ks = 0; ks < KS; ks++) {
        A0[ks] = short8{0,0,0,0,0,0,0,0};
        A1[ks] = short8{0,0,0,0,0,0,0,0};
    }
    if (s0 >= 0) {
        const unsigned short* ap = ge.X + (size_t)s0 * FIN + q * 8;
        #pragma unroll
        for (int ks = 0; ks < KS; ks++) A0[ks] = *(const short8*)(ap + ks * 32);
    }
    if (s1 >= 0) {
        const unsigned short* ap = ge.X + (size_t)s1 * FIN + q * 8;
        #pragma unroll
        for (int ks = 0; ks < KS; ks++) A1[ks] = *(const short8*)(ap + ks * 32);
    }

    floatx4 acc[2][NT];
    #pragma unroll
    for (int a = 0; a < 2; a++)
        #pragma unroll
        for (int nt = 0; nt < NT; nt++) acc[a][nt] = floatx4{0.f, 0.f, 0.f, 0.f};

    #pragma unroll
    for (int ks = 0; ks < KS; ks++) {
        int kk = ks * 32 + q * 8;
        #pragma unroll
        for (int nt = 0; nt < NT; nt++) {
            short8 bf = *(const short8*)&Us[(nt * 16 + ln) * LDK + kk];
            acc[0][nt] = __builtin_amdgcn_mfma_f32_16x16x32_bf16(A0[ks], bf, acc[0][nt], 0, 0, 0);
            acc[1][nt] = __builtin_amdgcn_mfma_f32_16x16x32_bf16(A1[ks], bf, acc[1][nt], 0, 0, 0);
        }
    }

    // epilogue: bf16 msgs through LDS (Us re-used), coalesced full-line scatter
    __syncthreads();   // everyone done reading Bs from Us
    #pragma unroll
    for (int mt = 0; mt < 2; mt++) {
        #pragma unroll
        for (int rr2 = 0; rr2 < 4; rr2++) {
            int i = mbase + mt * 16 + q * 4 + rr2;
            #pragma unroll
            for (int nt = 0; nt < NT; nt++)
                Us[i * LDM + nt * 16 + ln] = f2bf(acc[mt][nt][rr2]);
        }
    }
    __syncthreads();
    constexpr int CH = HOUT / 8;
    for (int c = tid; c < GBM * CH; c += 512) {
        int row = c / CH, cc = c % CH;
        if (row < mcount) {
            uint4e v = *(const uint4e*)&Us[row * LDM + cc * 8];
            *(uint4e*)&ge.msg[(size_t)Pd[row] * HOUT + cc * 8] = v;
        }
    }
}

// weighted segment-sum of msg rows per dst + root base; optional relu+bf16.
// DOUBLE accumulation keeps results independent of the (nondeterministic)
// edge->slot assignment order. blockIdx.y selects the encoding bundle.
template <int H, bool RELU>
__global__ void k_reduce(RedArgs ra, const int* __restrict__ dstOff) {
    const RedEnc re = ra.e[blockIdx.y];
    int d = blockIdx.x * 4 + (threadIdx.x >> 6);
    if (d >= NN) return;
    int lane = threadIdx.x & 63;
    constexpr int HC = H / 4;
    constexpr int RPI = 64 / HC;
    int sub = lane / HC;
    int c4 = lane % HC;
    int j0 = dstOff[d], j1 = dstOff[d + 1];
    double a0 = 0.0, a1 = 0.0, a2 = 0.0, a3 = 0.0;
    for (int j = j0 + sub; j < j1; j += RPI) {
        float w = re.wD[j];
        uint2e v = *(const uint2e*)&re.msg[(size_t)j * H + c4 * 4];
        a0 += (double)(w * bfbits2f(v.x << 16));
        a1 += (double)(w * bfbits2f(v.x & 0xffff0000u));
        a2 += (double)(w * bfbits2f(v.y << 16));
        a3 += (double)(w * bfbits2f(v.y & 0xffff0000u));
    }
    #pragma unroll
    for (int ofs = 32; ofs >= HC; ofs >>= 1) {
        a0 += __shfl_down(a0, ofs); a1 += __shfl_down(a1, ofs);
        a2 += __shfl_down(a2, ofs); a3 += __shfl_down(a3, ofs);
    }
    if (lane < HC) {
        size_t o = (size_t)d * H + c4 * 4;
        float v0 = re.base[o] + (float)a0, v1 = re.base[o + 1] + (float)a1;
        float v2 = re.base[o + 2] + (float)a2, v3 = re.base[o + 3] + (float)a3;
        if (RELU) {
            v0 = fmaxf(v0, 0.f); v1 = fmaxf(v1, 0.f);
            v2 = fmaxf(v2, 0.f); v3 = fmaxf(v3, 0.f);
        }
        re.base[o] = v0; re.base[o + 1] = v1; re.base[o + 2] = v2; re.base[o + 3] = v3;
        if (RELU) {
            re.bfout[o] = f2bf(v0); re.bfout[o + 1] = f2bf(v1);
            re.bfout[o + 2] = f2bf(v2); re.bfout[o + 3] = f2bf(v3);
        }
    }
}

// column partial sums of x2_o -> part[block][32] (plain stores, deterministic)
__global__ void k_mean(const float* __restrict__ x2o, float* __restrict__ part) {
    __shared__ float s[256];
    int t = threadIdx.x; int hh = t & 31; int g = t >> 5;
    float acc = 0.f;
    for (int n = blockIdx.x * 8 + g; n < NN; n += gridDim.x * 8)
        acc += x2o[(size_t)n * 32 + hh];
    s[t] = acc;
    __syncthreads();
    if (t < 32) {
        float v = 0.f;
        for (int gg = 0; gg < 8; gg++) v += s[gg * 32 + t];
        part[blockIdx.x * 32 + t] = v;
    }
}

// deterministic final column sum: csum[c] = sum_b part[b][c] in fixed order
__global__ void k_csum(const float* __restrict__ part, float* __restrict__ csum) {
    int t = threadIdx.x;
    if (t < 32) {
        double a = 0.0;
        for (int b = 0; b < 256; b++) a += (double)part[b * 32 + t];
        csum[t] = (float)a;
    }
}

// c = sigmoid(csum/N); v = disc_W @ c; bilinear scores
__global__ void k_disc(const float* __restrict__ x2o, const float* __restrict__ x2a,
                       const float* __restrict__ x2aa, const float* __restrict__ csum,
                       const float* __restrict__ discW, const float* __restrict__ discb,
                       float* ret_os, float* ret_osa) {
    __shared__ float c[32], v[32];
    int t = threadIdx.x;
    if (t < 32) c[t] = 1.f / (1.f + expf(-csum[t] * (1.f / NN)));
    __syncthreads();
    if (t < 32) {
        float a = 0.f;
        for (int j = 0; j < 32; j++) a += discW[t * 32 + j] * c[j];
        v[t] = a;
    }
    __syncthreads();
    float db = discb[0];
    int n = blockIdx.x * 256 + t;
    if (n < NN) {
        float s1 = 0.f, s2 = 0.f, s3 = 0.f;
        for (int j = 0; j < 32; j++) {
            float vj = v[j];
            s1 += x2o[(size_t)n * 32 + j] * vj;
            s2 += x2a[(size_t)n * 32 + j] * vj;
            s3 += x2aa[(size_t)n * 32 + j] * vj;
        }
        ret_os[n * 2] = s1 + db;  ret_os[n * 2 + 1] = s2 + db;
        ret_osa[n * 2] = s1 + db; ret_osa[n * 2 + 1] = s3 + db;
    }
}

// pair classifier as MFMA GEMM (K padded to 512, N padded to 80)
__launch_bounds__(256, 2)
__global__ void k_clsg(const float* __restrict__ h1o, const float* __restrict__ x2o,
                       const float* __restrict__ feat, const float* __restrict__ attt,
                       const int* __restrict__ idx,
                       const unsigned short* __restrict__ cwt,
                       const float* __restrict__ clsb, float* __restrict__ log_out) {
    constexpr int LDK = CLS_CK + 8;
    __shared__ unsigned short As[CLS_BM][LDK];
    __shared__ unsigned short Bs[CLS_N][LDK];
    __shared__ int nd[2][CLS_BM];

    int tid = threadIdx.x;
    int p0 = blockIdx.x * CLS_BM;
    if (tid < CLS_BM) {
        nd[0][tid] = idx[p0 + tid];
        nd[1][tid] = idx[BB + p0 + tid];
    }
    float a0 = attt[0], a1 = attt[1];

    const int wave = tid >> 6;
    const int lane = tid & 63;
    const int q = lane >> 4;
    const int ln = lane & 15;
    constexpr int NT = CLS_N / 16;
    const int mbase = wave * 16;

    floatx4 acc[NT];
    #pragma unroll
    for (int nt = 0; nt < NT; nt++) acc[nt] = floatx4{0.f, 0.f, 0.f, 0.f};

    for (int ch = 0; ch < CLS_K / CLS_CK; ch++) {
        int kbase = ch * CLS_CK;
        __syncthreads();
        for (int c = tid; c < CLS_N * CLS_CK / 8; c += 256) {
            int row = c / (CLS_CK / 8), cc = c % (CLS_CK / 8);
            *(uint4*)&Bs[row][cc * 8] = *(const uint4*)&cwt[(size_t)row * CLS_K + kbase + cc * 8];
        }
        for (int c = tid; c < CLS_BM * CLS_CK / 4; c += 256) {
            int row = c / (CLS_CK / 4);
            int j4 = (c % (CLS_CK / 4)) * 4;
            int j = kbase + j4;
            float4 v = {0.f, 0.f, 0.f, 0.f};
            if (j < 448) {
                int hseg = j / 224, jj = j % 224;
                int node = nd[hseg][row];
                if (jj < 64) {
                    v = *(const float4*)&h1o[(size_t)node * 64 + jj];
                    v.x *= a0; v.y *= a0; v.z *= a0; v.w *= a0;
                } else if (jj < 96) {
                    v = *(const float4*)&x2o[(size_t)node * 32 + (jj - 64)];
                    v.x *= a1; v.y *= a1; v.z *= a1; v.w *= a1;
                } else {
                    v = *(const float4*)&feat[(size_t)node * 128 + (jj - 96)];
                }
            }
            uint2 pk;
            pk.x = (unsigned)f2bf(v.x) | ((unsigned)f2bf(v.y) << 16);
            pk.y = (unsigned)f2bf(v.z) | ((unsigned)f2bf(v.w) << 16);
            *(uint2*)&As[row][j4] = pk;
        }
        __syncthreads();
        #pragma unroll
        for (int ks = 0; ks < CLS_CK / 32; ks++) {
            int kk = ks * 32 + q * 8;
            short8 af = *(const short8*)&As[mbase + ln][kk];
            #pragma unroll
            for (int nt = 0; nt < NT; nt++) {
                short8 bf = *(const short8*)&Bs[nt * 16 + ln][kk];
                acc[nt] = __builtin_amdgcn_mfma_f32_16x16x32_bf16(af, bf, acc[nt], 0, 0, 0);
            }
        }
    }

    #pragma unroll
    for (int rr2 = 0; rr2 < 4; rr2++) {
        int i = mbase + q * 4 + rr2;
        int pair = p0 + i;
        #pragma unroll
        for (int nt = 0; nt < NT; nt++) {
            int col = nt * 16 + ln;
            if (col < RR)
                log_out[(size_t)pair * RR + col] = acc[nt][rr2] + clsb[col];
        }
    }
}

extern "C" void kernel_launch(void* const* d_in, const int* in_sizes, int n_in,
                              void* d_out, int out_size, void* d_ws, size_t ws_size,
                              hipStream_t stream) {
    const float* x_o   = (const float*)d_in[0];
    const float* x_a   = (const float*)d_in[1];
    const float* feat  = (const float*)d_in[2];
    const float* W1    = (const float*)d_in[3];
    const float* root1 = (const float*)d_in[4];
    const float* b1    = (const float*)d_in[5];
    const float* W2    = (const float*)d_in[6];
    const float* root2 = (const float*)d_in[7];
    const float* b2    = (const float*)d_in[8];
    const float* attt  = (const float*)d_in[9];
    const float* discW = (const float*)d_in[10];
    const float* discb = (const float*)d_in[11];
    const float* clsW  = (const float*)d_in[12];
    const float* clsb  = (const float*)d_in[13];
    const int* ei      = (const int*)d_in[14];
    const int* et0     = (const int*)d_in[15];
    const int* et1     = (const int*)d_in[16];
    const int* idx     = (const int*)d_in[17];

    char* ws = (char*)d_ws;
    float* csum = (float*)(ws + OFF_CSUM);
    int* cntD  = (int*)(ws + OFF_CNTD);
    int* dstOff = (int*)(ws + OFF_DSTOFF);
    int* bh0   = (int*)(ws + OFF_BH0);
    int* bh1   = (int*)(ws + OFF_BH1);
    int* bb0   = (int*)(ws + OFF_BB0);
    int* bb1   = (int*)(ws + OFF_BB1);
    int* hT    = (int*)(ws + OFF_HT);
    int* offB0 = (int*)(ws + OFF_OFFB0);
    int* offB1 = (int*)(ws + OFF_OFFB1);
    int* tilB0 = (int*)(ws + OFF_TILB0);
    int* tilT0 = (int*)(ws + OFF_TILT0);
    int* tilB1 = (int*)(ws + OFF_TILB1);
    int* tilT1 = (int*)(ws + OFF_TILT1);
    int* slotE = (int*)(ws + OFF_SLOT);
    int* posD  = (int*)(ws + OFF_POSD);
    unsigned int* rdP = (unsigned int*)(ws + OFF_RDP);
    float* wD0 = (float*)(ws + OFF_WD0);
    float* wD1 = (float*)(ws + OFF_WD1);
    unsigned int* perm0 = (unsigned int*)(ws + OFF_PERM0);
    unsigned int* perm1 = (unsigned int*)(ws + OFF_PERM1);
    unsigned short* xob = (unsigned short*)(ws + OFF_XOB);
    unsigned short* xab = (unsigned short*)(ws + OFF_XAB);
    float* h1o  = (float*)(ws + OFF_H1);
    float* h1a  = h1o + (size_t)NN * HH1;
    float* h1aa = h1a + (size_t)NN * HH1;
    unsigned short* h1bo  = (unsigned short*)(ws + OFF_H1B);
    unsigned short* h1ba  = h1bo + (size_t)NN * HH1;
    unsigned short* h1baa = h1ba + (size_t)NN * HH1;
    float* x2a  = (float*)(ws + OFF_X2A);
    float* x2aa = (float*)(ws + OFF_X2AA);
    unsigned short* w1t = (unsigned short*)(ws + OFF_W1BT);
    unsigned short* w2t = (unsigned short*)(ws + OFF_W2BT);
    unsigned short* r1t = (unsigned short*)(ws + OFF_R1T);
    unsigned short* r2t = (unsigned short*)(ws + OFF_R2T);
    unsigned short* cwt = (unsigned short*)(ws + OFF_CWT);
    float* part = (float*)(ws + OFF_PART);
    unsigned short* msg = (unsigned short*)(ws + OFF_MSG);

    float* out = (float*)d_out;
    float* log_out = out + O_LOG;
    float* ret_os  = out + O_ROS;
    float* ret_osa = out + O_ROSA;
    float* x2o     = out + O_X2O;

    // how many msg buffers fit? (runtime-tiered so any ws_size still works)
    size_t availMsg = ws_size > OFF_MSG ? ws_size - OFF_MSG : MSG_B1;
    int nb1 = (availMsg >= 2 * MSG_B1) ? 2 : 1;
    int nb2 = (availMsg >= 3 * MSG_B2) ? 3 : (availMsg >= 2 * MSG_B2 ? 2 : 1);

    // 1) zero control block (csum + cntD) — ~80 KB
    hipMemsetAsync(ws, 0, ZERO_BYTES, stream);

    // 2) preprocessing: (octile,relation) bucket sort with packed metadata
    k_hist<<<GRID_PRE, 256, 0, stream>>>(ei, et0, et1, cntD, slotE, bh0, bh1,
                                         x_o, x_a, W1, W2, root1, root2, clsW,
                                         xob, xab, w1t, w2t, r1t, r2t, cwt);
    k_scanD<<<1, 256, 0, stream>>>(cntD, dstOff);
    k_post<<<2500, 256, 0, stream>>>(ei, et0, et1, dstOff, slotE, posD, rdP);
    k_scanB1<<<(2 * NB2 + 3) / 4, 256, 0, stream>>>(bh0, bh1, bb0, bb1, hT);
    k_scanB2<<<1, 256, 0, stream>>>(hT, offB0, offB1,
                                    tilB0, tilT0, tilB1, tilT1);
    k_fillB<<<NBH, 256, 0, stream>>>(ei, et0, et1, posD, offB0, offB1, bb0, bb1,
                                     perm0, perm1);
    k_wts<<<NN / 4, 256, 0, stream>>>(dstOff, rdP, wD0, wD1);

    // 3) layer 1: MFMA root GEMM + grouped (edge GEMM -> weighted reduce)
    {
        dim3 gb(NBT, 3);
        k_bgemm<FIN1, HH1><<<gb, 256, 0, stream>>>(xob, xab, xob, r1t, b1,
                                                   h1o, h1a, h1aa);
        const unsigned short* Xs[3] = {xob, xab, xob};
        float* Os[3] = {h1o, h1a, h1aa};
        unsigned short* Obs[3] = {h1bo, h1ba, h1baa};
        for (int e0 = 0; e0 < 3; ) {
            int g = 3 - e0 < nb1 ? 3 - e0 : nb1;
            GemmArgs ga{};
            RedArgs ra{};
            for (int j = 0; j < g; j++) {
                int enc = e0 + j;
                unsigned short* mb = msg + (size_t)j * EE * HH1;
                ga.e[j].X    = Xs[enc];
                ga.e[j].msg  = mb;
                ga.e[j].perm = enc == 2 ? perm1 : perm0;
                ga.e[j].offB = enc == 2 ? offB1 : offB0;
                ga.e[j].tilB = enc == 2 ? tilB1 : tilB0;
                ga.e[j].tilT = enc == 2 ? tilT1 : tilT0;
                ra.e[j].msg  = mb;
                ra.e[j].wD   = enc == 2 ? wD1 : wD0;
                ra.e[j].base = Os[enc];
                ra.e[j].bfout = Obs[enc];
            }
            k_gemm<FIN1, HH1><<<dim3(MAXT2, g), 512, 0, stream>>>(ga, w1t);
            k_reduce<HH1, true><<<dim3(NN / 4, g), 256, 0, stream>>>(ra, dstOff);
            e0 += g;
        }
    }

    // 4) layer 2: MFMA root GEMM + grouped (edge GEMM -> weighted reduce)
    {
        dim3 gb(NBT, 3);
        k_bgemm<HH1, HH2><<<gb, 256, 0, stream>>>(h1bo, h1ba, h1baa, r2t, b2,
                                                  x2o, x2a, x2aa);
        const unsigned short* Xs[3] = {h1bo, h1ba, h1baa};
        float* Os[3] = {x2o, x2a, x2aa};
        for (int e0 = 0; e0 < 3; ) {
            int g = 3 - e0 < nb2 ? 3 - e0 : nb2;
            GemmArgs ga{};
            RedArgs ra{};
            for (int j = 0; j < g; j++) {
                int enc = e0 + j;
                unsigned short* mb = msg + (size_t)j * EE * HH2;
                ga.e[j].X    = Xs[enc];
                ga.e[j].msg  = mb;
                ga.e[j].perm = enc == 2 ? perm1 : perm0;
                ga.e[j].offB = enc == 2 ? offB1 : offB0;
                ga.e[j].tilB = enc == 2 ? tilB1 : tilB0;
                ga.e[j].tilT = enc == 2 ? tilT1 : tilT0;
                ra.e[j].msg  = mb;
                ra.e[j].wD   = enc == 2 ? wD1 : wD0;
                ra.e[j].base = Os[enc];
                ra.e[j].bfout = nullptr;
            }
            k_gemm<HH1, HH2><<<dim3(MAXT2, g), 512, 0, stream>>>(ga, w2t);
            k_reduce<HH2, false><<<dim3(NN / 4, g), 256, 0, stream>>>(ra, dstOff);
            e0 += g;
        }
    }

    // 5) readout + discriminator + classifier
    k_mean<<<256, 256, 0, stream>>>(x2o, part);
    k_csum<<<1, 64, 0, stream>>>(part, csum);
    k_disc<<<(NN + 255) / 256, 256, 0, stream>>>(x2o, x2a, x2aa, csum, discW, discb,
                                                 ret_os, ret_osa);
    k_clsg<<<BB / CLS_BM, 256, 0, stream>>>(h1o, x2o, feat, attt, idx, cwt, clsb, log_out);
}

// Round 10
// 522.493 us; speedup vs baseline: 1.1545x; 1.0637x over previous
//
#include <hip/hip_runtime.h>
#include <hip/hip_bf16.h>

// ---------------- problem constants ----------------
#define NN 20000      // nodes
#define EE 640000     // edges
#define RR 65         // relations
#define FIN1 128      // input feat
#define HH1 64        // hidden1
#define HH2 32        // hidden2
#define BB 8192       // pairs

constexpr int BM = 128;                 // node-tile rows (root GEMM)
constexpr int GBM = 256;                // edge-tile rows per gather-GEMM block
constexpr int NBH = 256;                // histogram/placement blocks
constexpr int GRID_PRE = 2048;          // k_hist launch grid (occupancy for conversions)
constexpr int EPB = EE / NBH;           // 2500 edges per block
constexpr int NBT = (NN + BM - 1) / BM; // 157 node tiles
constexpr int NOCT = 8;                 // src octiles (nodes per octile = 2500)
constexpr int NPO = NN / NOCT;          // 2500
constexpr int NB2 = NOCT * RR;          // 520 sort buckets (octile-major, relation inner)
constexpr int MAXT2 = EE / GBM + NB2;   // 3020 tile upper bound (256-edge tiles)

// classifier GEMM geometry (E[8192x448] @ clsW[448x65], padded)
constexpr int CLS_K  = 512;
constexpr int CLS_N  = 80;
constexpr int CLS_CK = 128;
constexpr int CLS_BM = 64;
constexpr int NCLSB  = BB / CLS_BM;     // 128 classifier blocks
constexpr int NDISCB = (NN + 255) / 256; // 79 disc blocks

typedef __attribute__((ext_vector_type(8))) short short8;   // 8 bf16 MFMA frag
typedef __attribute__((ext_vector_type(4))) float floatx4;  // 4 fp32 acc
typedef __attribute__((ext_vector_type(4))) unsigned int uint4e;  // 16B vector
typedef __attribute__((ext_vector_type(2))) unsigned int uint2e;  // 8B vector

// ---------------- workspace layout (bytes) ----------------
constexpr size_t aln(size_t x) { return (x + 255) & ~(size_t)255; }

constexpr size_t OFF_CSUM  = 0;                        // 32 f
constexpr size_t OFF_CNTD  = aln(OFF_CSUM + 32 * 4);  // NN int (dst degree)
constexpr size_t ZERO_BYTES = OFF_CNTD + (size_t)NN * 4;   // memset [0, ZERO_BYTES)
constexpr size_t OFF_DSTOFF = aln(ZERO_BYTES);         // NN+1 int
constexpr size_t OFF_BH0   = aln(OFF_DSTOFF + ((size_t)NN + 1) * 4); // NBH*NB2
constexpr size_t OFF_BH1   = OFF_BH0 + (size_t)NBH * NB2 * 4;
constexpr size_t OFF_BB0   = OFF_BH1 + (size_t)NBH * NB2 * 4;
constexpr size_t OFF_BB1   = OFF_BB0 + (size_t)NBH * NB2 * 4;
constexpr size_t OFF_HT    = aln(OFF_BB1 + (size_t)NBH * NB2 * 4);   // 2*NB2 int totals
constexpr size_t OFF_OFFB0 = aln(OFF_HT + (size_t)2 * NB2 * 4);      // NB2+1 int
constexpr size_t OFF_OFFB1 = OFF_OFFB0 + (NB2 + 1) * 4;
constexpr size_t OFF_TILB0 = aln(OFF_OFFB1 + (NB2 + 1) * 4);  // MAXT2 int
constexpr size_t OFF_TILT0 = OFF_TILB0 + (size_t)MAXT2 * 4;
constexpr size_t OFF_TILB1 = OFF_TILT0 + (size_t)MAXT2 * 4;
constexpr size_t OFF_TILT1 = OFF_TILB1 + (size_t)MAXT2 * 4;
constexpr size_t OFF_SLOT  = aln(OFF_TILT1 + (size_t)MAXT2 * 4);  // E int
constexpr size_t OFF_POSD  = OFF_SLOT + (size_t)EE * 4;           // E int (e -> dst pos)
constexpr size_t OFF_RDP   = OFF_POSD + (size_t)EE * 4;           // E uint (pos -> r0|r1<<16)
constexpr size_t OFF_WD0   = OFF_RDP + (size_t)EE * 4;            // E float (pos-space weights)
constexpr size_t OFF_WD1   = OFF_WD0 + (size_t)EE * 4;
constexpr size_t OFF_PERM0 = OFF_WD1 + (size_t)EE * 4;            // E uint (srcLocal<<20|pos)
constexpr size_t OFF_PERM1 = OFF_PERM0 + (size_t)EE * 4;
constexpr size_t OFF_XOB   = aln(OFF_PERM1 + (size_t)EE * 4);     // N*F bf16
constexpr size_t OFF_XAB   = OFF_XOB + (size_t)NN * FIN1 * 2;
constexpr size_t OFF_H1    = aln(OFF_XAB + (size_t)NN * FIN1 * 2); // 3 * N*64 f
constexpr size_t OFF_H1B   = OFF_H1 + (size_t)3 * NN * HH1 * 4;    // 3 * N*64 bf16
constexpr size_t OFF_X2A   = OFF_H1B + (size_t)3 * NN * HH1 * 2;   // N*32 f
constexpr size_t OFF_X2AA  = OFF_X2A + (size_t)NN * HH2 * 4;
constexpr size_t OFF_W1BT  = OFF_X2AA + (size_t)NN * HH2 * 4;      // R*64*128 bf16
constexpr size_t OFF_W2BT  = OFF_W1BT + (size_t)RR * HH1 * FIN1 * 2;
constexpr size_t OFF_R1T   = OFF_W2BT + (size_t)RR * HH2 * HH1 * 2;
constexpr size_t OFF_R2T   = OFF_R1T + (size_t)HH1 * FIN1 * 2;
constexpr size_t OFF_CWT   = OFF_R2T + (size_t)HH2 * HH1 * 2;
constexpr size_t OFF_PART  = aln(OFF_CWT + (size_t)CLS_N * CLS_K * 2); // 256*32 f partials
constexpr size_t OFF_MSG   = aln(OFF_PART + (size_t)256 * 32 * 4);     // msg buffers (1..3)
constexpr size_t MSG_B1    = (size_t)EE * HH1 * 2;   // one layer-1 msg buffer
constexpr size_t MSG_B2    = (size_t)EE * HH2 * 2;   // one layer-2 msg buffer
constexpr size_t WS_END    = OFF_MSG + MSG_B1;       // minimum required (1 buffer)

// output offsets (floats)
constexpr size_t O_LOG  = 0;
constexpr size_t O_ROS  = (size_t)BB * RR;
constexpr size_t O_ROSA = O_ROS + (size_t)NN * 2;
constexpr size_t O_X2O  = O_ROSA + (size_t)NN * 2;

__device__ inline unsigned short f2bf(float f) {
    __hip_bfloat16 h = __float2bfloat16(f);
    return *reinterpret_cast<unsigned short*>(&h);
}
__device__ inline float bfbits2f(unsigned int hi_bits) {
    return __uint_as_float(hi_bits);
}

// per-enc pointer bundles for merged launches
struct GemmEnc {
    const unsigned short* X;
    unsigned short* msg;
    const unsigned int* perm;
    const int* offB;
    const int* tilB;
    const int* tilT;
    float* obase;                 // root-GEMM output (merged root role)
};
struct GemmArgs { GemmEnc e[3]; };

struct RedEnc {
    const unsigned short* msg;
    const float* wD;
    float* base;
    unsigned short* bfout;
};
struct RedArgs { RedEnc e[3]; };

// ---------------- preprocessing ----------------
__global__ void k_hist(const int* __restrict__ ei, const int* __restrict__ et0,
                       const int* __restrict__ et1,
                       int* cntD, int* __restrict__ slotE,
                       int* __restrict__ bh0, int* __restrict__ bh1,
                       const float* __restrict__ x_o, const float* __restrict__ x_a,
                       const float* __restrict__ W1, const float* __restrict__ W2,
                       const float* __restrict__ root1, const float* __restrict__ root2,
                       const float* __restrict__ clsW,
                       unsigned short* xob, unsigned short* xab,
                       unsigned short* w1t, unsigned short* w2t,
                       unsigned short* r1t, unsigned short* r2t,
                       unsigned short* cwt) {
    __shared__ int lh0[NB2], lh1[NB2];
    int t = threadIdx.x;
    if (blockIdx.x < NBH) {
        for (int p = t; p < NB2; p += 256) { lh0[p] = 0; lh1[p] = 0; }
        __syncthreads();
        int base = blockIdx.x * EPB;
        for (int i = t; i < EPB; i += 256) {
            int e = base + i;
            int oct = ei[e] / NPO;
            atomicAdd(&lh0[oct * RR + et0[e]], 1);
            atomicAdd(&lh1[oct * RR + et1[e]], 1);
            slotE[e] = atomicAdd(&cntD[ei[EE + e]], 1);
        }
        __syncthreads();
        for (int p = t; p < NB2; p += 256) {
            bh0[blockIdx.x * NB2 + p] = lh0[p];
            bh1[blockIdx.x * NB2 + p] = lh1[p];
        }
    }
    // streaming conversions (grid-stride, vectorized 4-wide)
    int stride = gridDim.x * 256;
    int i0 = blockIdx.x * 256 + t;
    const int NX4 = NN * FIN1 / 4;
    const float4* xo4 = (const float4*)x_o;
    const float4* xa4 = (const float4*)x_a;
    for (int i = i0; i < NX4; i += stride) {
        float4 a = xo4[i], b = xa4[i];
        uint2 pa, pb;
        pa.x = (unsigned)f2bf(a.x) | ((unsigned)f2bf(a.y) << 16);
        pa.y = (unsigned)f2bf(a.z) | ((unsigned)f2bf(a.w) << 16);
        pb.x = (unsigned)f2bf(b.x) | ((unsigned)f2bf(b.y) << 16);
        pb.y = (unsigned)f2bf(b.z) | ((unsigned)f2bf(b.w) << 16);
        ((uint2*)xob)[i] = pa;
        ((uint2*)xab)[i] = pb;
    }
    const int NW1_4 = RR * HH1 * FIN1 / 4;
    for (int i4 = i0; i4 < NW1_4; i4 += stride) {
        int i = i4 * 4;
        int k = i % FIN1; int rh = i / FIN1; int hh = rh % HH1; int r = rh / HH1;
        const float* s = &W1[((size_t)r * FIN1 + k) * HH1 + hh];
        uint2 pk;
        pk.x = (unsigned)f2bf(s[0]) | ((unsigned)f2bf(s[HH1]) << 16);
        pk.y = (unsigned)f2bf(s[2 * HH1]) | ((unsigned)f2bf(s[3 * HH1]) << 16);
        ((uint2*)w1t)[i4] = pk;
    }
    const int NW2_4 = RR * HH2 * HH1 / 4;
    for (int i4 = i0; i4 < NW2_4; i4 += stride) {
        int i = i4 * 4;
        int k = i % HH1; int rh = i / HH1; int hh = rh % HH2; int r = rh / HH2;
        const float* s = &W2[((size_t)r * HH1 + k) * HH2 + hh];
        uint2 pk;
        pk.x = (unsigned)f2bf(s[0]) | ((unsigned)f2bf(s[HH2]) << 16);
        pk.y = (unsigned)f2bf(s[2 * HH2]) | ((unsigned)f2bf(s[3 * HH2]) << 16);
        ((uint2*)w2t)[i4] = pk;
    }
    const int NR1_4 = HH1 * FIN1 / 4;
    for (int i4 = i0; i4 < NR1_4; i4 += stride) {
        int i = i4 * 4;
        int k = i % FIN1; int hh = i / FIN1;
        const float* s = &root1[(size_t)k * HH1 + hh];
        uint2 pk;
        pk.x = (unsigned)f2bf(s[0]) | ((unsigned)f2bf(s[HH1]) << 16);
        pk.y = (unsigned)f2bf(s[2 * HH1]) | ((unsigned)f2bf(s[3 * HH1]) << 16);
        ((uint2*)r1t)[i4] = pk;
    }
    const int NR2_4 = HH2 * HH1 / 4;
    for (int i4 = i0; i4 < NR2_4; i4 += stride) {
        int i = i4 * 4;
        int k = i % HH1; int hh = i / HH1;
        const float* s = &root2[(size_t)k * HH2 + hh];
        uint2 pk;
        pk.x = (unsigned)f2bf(s[0]) | ((unsigned)f2bf(s[HH2]) << 16);
        pk.y = (unsigned)f2bf(s[2 * HH2]) | ((unsigned)f2bf(s[3 * HH2]) << 16);
        ((uint2*)r2t)[i4] = pk;
    }
    const int NCW_4 = CLS_N * CLS_K / 4;
    for (int i4 = i0; i4 < NCW_4; i4 += stride) {
        int i = i4 * 4;
        int k = i % CLS_K; int n = i / CLS_K;
        uint2 pk = {0u, 0u};
        if (n < RR && k < 448) {
            const float* s = &clsW[(size_t)k * RR + n];
            pk.x = (unsigned)f2bf(s[0]) | ((unsigned)f2bf(s[RR]) << 16);
            pk.y = (unsigned)f2bf(s[2 * RR]) | ((unsigned)f2bf(s[3 * RR]) << 16);
        }
        ((uint2*)cwt)[i4] = pk;
    }
}

// FUSED A: block 0 = exclusive dst-degree scan; blocks 1.. = per-bucket
// column scans (independent chains, both depend only on k_hist).
__global__ void k_scanA(const int* __restrict__ cntD, int* __restrict__ dstOff,
                        const int* __restrict__ bh0, const int* __restrict__ bh1,
                        int* __restrict__ bb0, int* __restrict__ bb1,
                        int* __restrict__ hT) {
    int t = threadIdx.x;
    if (blockIdx.x == 0) {
        __shared__ int s[256];
        constexpr int PER = (NN + 255) / 256;
        int lo = t * PER, hi = min(NN, lo + PER);
        int sum = 0;
        for (int i = lo; i < hi; i++) sum += cntD[i];
        s[t] = sum;
        __syncthreads();
        for (int ofs = 1; ofs < 256; ofs <<= 1) {
            int v = 0;
            if (t >= ofs) v = s[t - ofs];
            __syncthreads();
            if (t >= ofs) s[t] += v;
            __syncthreads();
        }
        int run = s[t] - sum;
        for (int i = lo; i < hi; i++) { dstOff[i] = run; run += cntD[i]; }
        if (t == 255) dstOff[NN] = run;
        return;
    }
    int w = (blockIdx.x - 1) * 4 + (t >> 6);
    int lane = t & 63;
    if (w >= 2 * NB2) return;
    int s = w / NB2, k = w % NB2;
    const int* bh = s ? bh1 : bh0;
    int* bb = s ? bb1 : bb0;
    int v[4];
    #pragma unroll
    for (int i = 0; i < 4; i++) v[i] = bh[(size_t)(lane * 4 + i) * NB2 + k];
    int ls = v[0] + v[1] + v[2] + v[3];
    int inc = ls;
    #pragma unroll
    for (int ofs = 1; ofs < 64; ofs <<= 1) {
        int o = __shfl_up(inc, ofs);
        if (lane >= ofs) inc += o;
    }
    int run = inc - ls;
    #pragma unroll
    for (int i = 0; i < 4; i++) {
        bb[(size_t)(lane * 4 + i) * NB2 + k] = run;
        run += v[i];
    }
    if (lane == 63) hT[s * NB2 + k] = run;
}

// FUSED B: blocks [0,2500) = posD/rdP placement; block 2500 = bucket offsets
// + tile tables (needs hT from A; post needs dstOff from A).
__global__ void k_postB(const int* __restrict__ ei, const int* __restrict__ et0,
                        const int* __restrict__ et1, const int* __restrict__ dstOff,
                        const int* __restrict__ slotE,
                        int* __restrict__ posD, unsigned int* __restrict__ rdP,
                        const int* __restrict__ hT,
                        int* offB0, int* offB1,
                        int* tilB0, int* tilT0, int* tilB1, int* tilT1) {
    int t = threadIdx.x;
    if (blockIdx.x < 2500) {
        int e = blockIdx.x * 256 + t;
        if (e < EE) {
            int d = ei[EE + e];
            int pos = dstOff[d] + slotE[e];
            posD[e] = pos;
            rdP[pos] = (unsigned)et0[e] | ((unsigned)et1[e] << 16);
        }
        return;
    }
    // scanB2 role (single block)
    __shared__ int h[2][NB2];
    __shared__ int o[2][NB2 + 1];
    __shared__ int to[2][NB2 + 1];
    __shared__ int csumE[2][8], csumT[2][8];
    for (int p = t; p < 2 * NB2; p += 256) h[p / NB2][p % NB2] = hT[p];
    __syncthreads();
    if (t < 16) {
        int s = t / 8, c = t % 8;
        int runE = 0, runT = 0;
        for (int k = c * RR; k < (c + 1) * RR; k++) {
            o[s][k] = runE;  runE += h[s][k];
            to[s][k] = runT; runT += (h[s][k] + GBM - 1) / GBM;
        }
        csumE[s][c] = runE; csumT[s][c] = runT;
    }
    __syncthreads();
    if (t < 2) {
        int runE = 0, runT = 0;
        for (int c = 0; c < 8; c++) {
            int e = csumE[t][c], tt = csumT[t][c];
            csumE[t][c] = runE; csumT[t][c] = runT;
            runE += e; runT += tt;
        }
        o[t][NB2] = runE; to[t][NB2] = runT;
    }
    __syncthreads();
    if (t < 16) {
        int s = t / 8, c = t % 8;
        for (int k = c * RR; k < (c + 1) * RR; k++) {
            o[s][k] += csumE[s][c];
            to[s][k] += csumT[s][c];
        }
    }
    __syncthreads();
    for (int p = t; p <= NB2; p += 256) { offB0[p] = o[0][p]; offB1[p] = o[1][p]; }
    for (int i = t; i < MAXT2; i += 256) {
        #pragma unroll
        for (int s = 0; s < 2; s++) {
            int total = to[s][NB2];
            int bkt = -1, ti = 0;
            if (i < total) {
                int lo = 0, hi = NB2;
                while (hi - lo > 1) { int mid = (lo + hi) >> 1; if (to[s][mid] <= i) lo = mid; else hi = mid; }
                bkt = lo;
                ti = i - to[s][lo];
            }
            if (s == 0) { tilB0[i] = bkt; tilT0[i] = ti; }
            else        { tilB1[i] = bkt; tilT1[i] = ti; }
        }
    }
}

// FUSED C: blocks [0,NBH) = perm placement; blocks [NBH,..) = per-(rel,dst)
// mean weights (fillB needs posD/offB/bb; wts needs dstOff/rdP — all ready).
__global__ void k_fillC(const int* __restrict__ ei, const int* __restrict__ et0,
                        const int* __restrict__ et1, const int* __restrict__ posD,
                        const int* __restrict__ offB0, const int* __restrict__ offB1,
                        const int* __restrict__ bb0, const int* __restrict__ bb1,
                        unsigned int* perm0, unsigned int* perm1,
                        const int* __restrict__ dstOff, const unsigned int* __restrict__ rdP,
                        float* __restrict__ wD0, float* __restrict__ wD1) {
    int t = threadIdx.x;
    if (blockIdx.x < NBH) {
        __shared__ int lc[2][NB2];
        __shared__ int lb[2][NB2];
        for (int p = t; p < NB2; p += 256) {
            lc[0][p] = 0; lc[1][p] = 0;
            lb[0][p] = offB0[p] + bb0[blockIdx.x * NB2 + p];
            lb[1][p] = offB1[p] + bb1[blockIdx.x * NB2 + p];
        }
        __syncthreads();
        int base = blockIdx.x * EPB;
        for (int i = t; i < EPB; i += 256) {
            int e = base + i;
            int src = ei[e];
            int pos = posD[e];
            int oct = src / NPO;
            unsigned int packed = ((unsigned)(src - oct * NPO) << 20) | (unsigned)pos;
            int k0 = oct * RR + et0[e];
            int k1 = oct * RR + et1[e];
            int p0 = atomicAdd(&lc[0][k0], 1);
            int p1 = atomicAdd(&lc[1][k1], 1);
            perm0[lb[0][k0] + p0] = packed;
            perm1[lb[1][k1] + p1] = packed;
        }
        return;
    }
    // wts role
    constexpr int CAP = 96;
    __shared__ unsigned int ld[4][CAP];
    int wave = t >> 6;
    int lane = t & 63;
    int d = (blockIdx.x - NBH) * 4 + wave;
    int j0 = 0, deg = 0;
    if (d < NN) { j0 = dstOff[d]; deg = dstOff[d + 1] - j0; }
    for (int j = lane; j < deg && j < CAP; j += 64) ld[wave][j] = rdP[j0 + j];
    __syncthreads();
    for (int j = lane; j < deg; j += 64) {
        unsigned int my = (j < CAP) ? ld[wave][j] : rdP[j0 + j];
        unsigned int m0 = my & 0xffffu, m1 = my >> 16;
        int c0 = 0, c1 = 0;
        for (int k = 0; k < deg; k++) {
            unsigned int p = (k < CAP) ? ld[wave][k] : rdP[j0 + k];
            c0 += ((p & 0xffffu) == m0);
            c1 += ((p >> 16) == m1);
        }
        wD0[j0 + j] = 1.0f / (float)c0;
        wD1[j0 + j] = 1.0f / (float)c1;
    }
}

// standalone root-term GEMM (fallback path when L1 can't run as one g=3)
template <int FIN, int HOUT>
__launch_bounds__(256, 3)
__global__ void k_bgemm(const unsigned short* __restrict__ X0,
                        const unsigned short* __restrict__ X1,
                        const unsigned short* __restrict__ X2,
                        const unsigned short* __restrict__ rootT,
                        const float* __restrict__ bias,
                        float* O0, float* O1, float* O2) {
    const int enc = blockIdx.y;
    const unsigned short* X = enc == 0 ? X0 : enc == 1 ? X1 : X2;
    float* O = enc == 0 ? O0 : enc == 1 ? O1 : O2;
    int n0 = blockIdx.x * BM;
    int mcount = min(BM, NN - n0);

    constexpr int LDK = FIN + 8;
    __shared__ unsigned short As[BM][LDK];
    __shared__ unsigned short Bs[HOUT][LDK];

    int tid = threadIdx.x;
    {
        constexpr int CHB = HOUT * FIN / 8;
        for (int c = tid; c < CHB; c += 256) {
            int row = c / (FIN / 8), cc = c % (FIN / 8);
            *(uint4*)&Bs[row][cc * 8] = *(const uint4*)&rootT[row * FIN + cc * 8];
        }
    }
    {
        constexpr int CHA = BM * FIN / 8;
        for (int c = tid; c < CHA; c += 256) {
            int row = c / (FIN / 8), cc = c % (FIN / 8);
            uint4 v = {0u, 0u, 0u, 0u};
            if (row < mcount) v = *(const uint4*)&X[(size_t)(n0 + row) * FIN + cc * 8];
            *(uint4*)&As[row][cc * 8] = v;
        }
    }
    __syncthreads();

    const int wave = tid >> 6;
    const int lane = tid & 63;
    const int q = lane >> 4;
    const int ln = lane & 15;
    constexpr int NT = HOUT / 16;
    constexpr int KS = FIN / 32;
    const int mbase = wave * 32;

    floatx4 acc[2][NT];
    #pragma unroll
    for (int a = 0; a < 2; a++)
        #pragma unroll
        for (int nt = 0; nt < NT; nt++) acc[a][nt] = floatx4{0.f, 0.f, 0.f, 0.f};

    for (int ks = 0; ks < KS; ks++) {
        int kk = ks * 32 + q * 8;
        short8 af0 = *(const short8*)&As[mbase + ln][kk];
        short8 af1 = *(const short8*)&As[mbase + 16 + ln][kk];
        #pragma unroll
        for (int nt = 0; nt < NT; nt++) {
            short8 bf = *(const short8*)&Bs[nt * 16 + ln][kk];
            acc[0][nt] = __builtin_amdgcn_mfma_f32_16x16x32_bf16(af0, bf, acc[0][nt], 0, 0, 0);
            acc[1][nt] = __builtin_amdgcn_mfma_f32_16x16x32_bf16(af1, bf, acc[1][nt], 0, 0, 0);
        }
    }

    #pragma unroll
    for (int mt = 0; mt < 2; mt++) {
        #pragma unroll
        for (int rr2 = 0; rr2 < 4; rr2++) {
            int i = mbase + mt * 16 + q * 4 + rr2;
            int n = n0 + i;
            if (i < mcount) {
                #pragma unroll
                for (int nt = 0; nt < NT; nt++)
                    O[(size_t)n * HOUT + nt * 16 + ln] = acc[mt][nt][rr2] + bias[nt * 16 + ln];
            }
        }
    }
}

// MERGED gemm: blockIdx.x < NBT -> ROOT role (contiguous node rows, A in
// regs, rootT in Us, fp32+bias epilogue); else EDGE role = R9 gather-GEMM
// (GBM=256 tile, A regs, B in LDS, bf16 msg scatter via Us). One launch
// replaces bgemm + edge-gemm. Per-output MFMA chains identical to the
// standalone kernels -> bitwise-identical results.
template <int FIN, int HOUT>
__launch_bounds__(512, 8)
__global__ void k_mgemm(GemmArgs ga, const unsigned short* __restrict__ WT,
                        const unsigned short* __restrict__ rootT,
                        const float* __restrict__ bias) {
    const GemmEnc ge = ga.e[blockIdx.y];
    constexpr int LDK = FIN + 8;
    constexpr int LDM = HOUT + 8;
    constexpr int BSZ = HOUT * LDK;
    constexpr int MSZ = GBM * LDM;
    constexpr int USZ = BSZ > MSZ ? BSZ : MSZ;
    __shared__ unsigned short Us[USZ];
    __shared__ int Sr[GBM];
    __shared__ int Pd[GBM];

    int tid = threadIdx.x;
    const int wave = tid >> 6;
    const int lane = tid & 63;
    const int q = lane >> 4;
    const int ln = lane & 15;
    constexpr int NT = HOUT / 16;
    constexpr int KS = FIN / 32;

    if (blockIdx.x < NBT) {
        // ---- ROOT role ----
        int n0 = blockIdx.x * BM;
        int mcount = min(BM, NN - n0);
        {
            constexpr int CHB = HOUT * FIN / 8;
            for (int c = tid; c < CHB; c += 512) {
                int row = c / (FIN / 8), cc = c % (FIN / 8);
                *(uint4*)&Us[row * LDK + cc * 8] = *(const uint4*)&rootT[row * FIN + cc * 8];
            }
        }
        __syncthreads();
        const int mbase = wave * 16;     // 8 waves x 16 rows = 128
        int i = mbase + ln;
        short8 A[KS];
        #pragma unroll
        for (int ks = 0; ks < KS; ks++) A[ks] = short8{0,0,0,0,0,0,0,0};
        if (i < mcount) {
            const unsigned short* ap = ge.X + (size_t)(n0 + i) * FIN + q * 8;
            #pragma unroll
            for (int ks = 0; ks < KS; ks++) A[ks] = *(const short8*)(ap + ks * 32);
        }
        floatx4 acc[NT];
        #pragma unroll
        for (int nt = 0; nt < NT; nt++) acc[nt] = floatx4{0.f, 0.f, 0.f, 0.f};
        #pragma unroll
        for (int ks = 0; ks < KS; ks++) {
            int kk = ks * 32 + q * 8;
            #pragma unroll
            for (int nt = 0; nt < NT; nt++) {
                short8 bf = *(const short8*)&Us[(nt * 16 + ln) * LDK + kk];
                acc[nt] = __builtin_amdgcn_mfma_f32_16x16x32_bf16(A[ks], bf, acc[nt], 0, 0, 0);
            }
        }
        #pragma unroll
        for (int rr2 = 0; rr2 < 4; rr2++) {
            int i2 = mbase + q * 4 + rr2;
            if (i2 < mcount) {
                #pragma unroll
                for (int nt = 0; nt < NT; nt++)
                    ge.obase[(size_t)(n0 + i2) * HOUT + nt * 16 + ln] = acc[nt][rr2] + bias[nt * 16 + ln];
            }
        }
        return;
    }

    // ---- EDGE role (R9 body) ----
    int b = blockIdx.x - NBT;
    int bkt = ge.tilB[b];
    if (bkt < 0) return;
    int r = bkt % RR;
    int srcBase = (bkt / RR) * NPO;
    int t = ge.tilT[b];
    int ebase = ge.offB[bkt] + t * GBM;
    int mcount = min(GBM, ge.offB[bkt + 1] - ebase);

    if (tid < GBM) {
        if (tid < mcount) {
            unsigned int p = ge.perm[ebase + tid];
            Sr[tid] = srcBase + (int)(p >> 20);
            Pd[tid] = (int)(p & 0xFFFFFu);
        } else { Sr[tid] = -1; Pd[tid] = 0; }
    }
    {
        const unsigned short* Wr = WT + (size_t)r * HOUT * FIN;
        constexpr int CHB = HOUT * FIN / 8;
        for (int c = tid; c < CHB; c += 512) {
            int row = c / (FIN / 8), cc = c % (FIN / 8);
            *(uint4*)&Us[row * LDK + cc * 8] = *(const uint4*)&Wr[row * FIN + cc * 8];
        }
    }
    __syncthreads();

    const int mbase = wave * 32;     // two 16-row m-tiles per wave

    int s0 = Sr[mbase + ln];
    int s1 = Sr[mbase + 16 + ln];
    short8 A0[KS], A1[KS];
    #pragma unroll
    for (int ks = 0; ks < KS; ks++) {
        A0[ks] = short8{0,0,0,0,0,0,0,0};
        A1[ks] = short8{0,0,0,0,0,0,0,0};
    }
    if (s0 >= 0) {
        const unsigned short* ap = ge.X + (size_t)s0 * FIN + q * 8;
        #pragma unroll
        for (int ks = 0; ks < KS; ks++) A0[ks] = *(const short8*)(ap + ks * 32);
    }
    if (s1 >= 0) {
        const unsigned short* ap = ge.X + (size_t)s1 * FIN + q * 8;
        #pragma unroll
        for (int ks = 0; ks < KS; ks++) A1[ks] = *(const short8*)(ap + ks * 32);
    }

    floatx4 acc[2][NT];
    #pragma unroll
    for (int a = 0; a < 2; a++)
        #pragma unroll
        for (int nt = 0; nt < NT; nt++) acc[a][nt] = floatx4{0.f, 0.f, 0.f, 0.f};

    #pragma unroll
    for (int ks = 0; ks < KS; ks++) {
        int kk = ks * 32 + q * 8;
        #pragma unroll
        for (int nt = 0; nt < NT; nt++) {
            short8 bf = *(const short8*)&Us[(nt * 16 + ln) * LDK + kk];
            acc[0][nt] = __builtin_amdgcn_mfma_f32_16x16x32_bf16(A0[ks], bf, acc[0][nt], 0, 0, 0);
            acc[1][nt] = __builtin_amdgcn_mfma_f32_16x16x32_bf16(A1[ks], bf, acc[1][nt], 0, 0, 0);
        }
    }

    __syncthreads();
    #pragma unroll
    for (int mt = 0; mt < 2; mt++) {
        #pragma unroll
        for (int rr2 = 0; rr2 < 4; rr2++) {
            int i = mbase + mt * 16 + q * 4 + rr2;
            #pragma unroll
            for (int nt = 0; nt < NT; nt++)
                Us[i * LDM + nt * 16 + ln] = f2bf(acc[mt][rr2 >= 0 ? nt : nt][rr2]);
        }
    }
    __syncthreads();
    constexpr int CH = HOUT / 8;
    for (int c = tid; c < GBM * CH; c += 512) {
        int row = c / CH, cc = c % CH;
        if (row < mcount) {
            uint4e v = *(const uint4e*)&Us[row * LDM + cc * 8];
            *(uint4e*)&ge.msg[(size_t)Pd[row] * HOUT + cc * 8] = v;
        }
    }
}

// R9 edge-only gather-GEMM (fallback path)
template <int FIN, int HOUT>
__launch_bounds__(512, 8)
__global__ void k_gemm(GemmArgs ga, const unsigned short* __restrict__ WT) {
    const GemmEnc ge = ga.e[blockIdx.y];
    int b = blockIdx.x;
    int bkt = ge.tilB[b];
    if (bkt < 0) return;
    int r = bkt % RR;
    int srcBase = (bkt / RR) * NPO;
    int t = ge.tilT[b];
    int ebase = ge.offB[bkt] + t * GBM;
    int mcount = min(GBM, ge.offB[bkt + 1] - ebase);

    constexpr int LDK = FIN + 8;
    constexpr int LDM = HOUT + 8;
    constexpr int BSZ = HOUT * LDK;
    constexpr int MSZ = GBM * LDM;
    constexpr int USZ = BSZ > MSZ ? BSZ : MSZ;
    __shared__ unsigned short Us[USZ];
    __shared__ int Sr[GBM];
    __shared__ int Pd[GBM];

    int tid = threadIdx.x;
    if (tid < GBM) {
        if (tid < mcount) {
            unsigned int p = ge.perm[ebase + tid];
            Sr[tid] = srcBase + (int)(p >> 20);
            Pd[tid] = (int)(p & 0xFFFFFu);
        } else { Sr[tid] = -1; Pd[tid] = 0; }
    }
    {
        const unsigned short* Wr = WT + (size_t)r * HOUT * FIN;
        constexpr int CHB = HOUT * FIN / 8;
        for (int c = tid; c < CHB; c += 512) {
            int row = c / (FIN / 8), cc = c % (FIN / 8);
            *(uint4*)&Us[row * LDK + cc * 8] = *(const uint4*)&Wr[row * FIN + cc * 8];
        }
    }
    __syncthreads();

    const int wave = tid >> 6;
    const int lane = tid & 63;
    const int q = lane >> 4;
    const int ln = lane & 15;
    constexpr int NT = HOUT / 16;
    constexpr int KS = FIN / 32;
    const int mbase = wave * 32;

    int s0 = Sr[mbase + ln];
    int s1 = Sr[mbase + 16 + ln];
    short8 A0[KS], A1[KS];
    #pragma unroll
    for (int ks = 0; ks < KS; ks++) {
        A0[ks] = short8{0,0,0,0,0,0,0,0};
        A1[ks] = short8{0,0,0,0,0,0,0,0};
    }
    if (s0 >= 0) {
        const unsigned short* ap = ge.X + (size_t)s0 * FIN + q * 8;
        #pragma unroll
        for (int ks = 0; ks < KS; ks++) A0[ks] = *(const short8*)(ap + ks * 32);
    }
    if (s1 >= 0) {
        const unsigned short* ap = ge.X + (size_t)s1 * FIN + q * 8;
        #pragma unroll
        for (int ks = 0; ks < KS; ks++) A1[ks] = *(const short8*)(ap + ks * 32);
    }

    floatx4 acc[2][NT];
    #pragma unroll
    for (int a = 0; a < 2; a++)
        #pragma unroll
        for (int nt = 0; nt < NT; nt++) acc[a][nt] = floatx4{0.f, 0.f, 0.f, 0.f};

    #pragma unroll
    for (int ks = 0; ks < KS; ks++) {
        int kk = ks * 32 + q * 8;
        #pragma unroll
        for (int nt = 0; nt < NT; nt++) {
            short8 bf = *(const short8*)&Us[(nt * 16 + ln) * LDK + kk];
            acc[0][nt] = __builtin_amdgcn_mfma_f32_16x16x32_bf16(A0[ks], bf, acc[0][nt], 0, 0, 0);
            acc[1][nt] = __builtin_amdgcn_mfma_f32_16x16x32_bf16(A1[ks], bf, acc[1][nt], 0, 0, 0);
        }
    }

    __syncthreads();
    #pragma unroll
    for (int mt = 0; mt < 2; mt++) {
        #pragma unroll
        for (int rr2 = 0; rr2 < 4; rr2++) {
            int i = mbase + mt * 16 + q * 4 + rr2;
            #pragma unroll
            for (int nt = 0; nt < NT; nt++)
                Us[i * LDM + nt * 16 + ln] = f2bf(acc[mt][nt][rr2]);
        }
    }
    __syncthreads();
    constexpr int CH = HOUT / 8;
    for (int c = tid; c < GBM * CH; c += 512) {
        int row = c / CH, cc = c % CH;
        if (row < mcount) {
            uint4e v = *(const uint4e*)&Us[row * LDM + cc * 8];
            *(uint4e*)&ge.msg[(size_t)Pd[row] * HOUT + cc * 8] = v;
        }
    }
}

// weighted segment-sum of msg rows per dst + root base; optional relu+bf16.
template <int H, bool RELU>
__global__ void k_reduce(RedArgs ra, const int* __restrict__ dstOff) {
    const RedEnc re = ra.e[blockIdx.y];
    int d = blockIdx.x * 4 + (threadIdx.x >> 6);
    if (d >= NN) return;
    int lane = threadIdx.x & 63;
    constexpr int HC = H / 4;
    constexpr int RPI = 64 / HC;
    int sub = lane / HC;
    int c4 = lane % HC;
    int j0 = dstOff[d], j1 = dstOff[d + 1];
    double a0 = 0.0, a1 = 0.0, a2 = 0.0, a3 = 0.0;
    for (int j = j0 + sub; j < j1; j += RPI) {
        float w = re.wD[j];
        uint2e v = *(const uint2e*)&re.msg[(size_t)j * H + c4 * 4];
        a0 += (double)(w * bfbits2f(v.x << 16));
        a1 += (double)(w * bfbits2f(v.x & 0xffff0000u));
        a2 += (double)(w * bfbits2f(v.y << 16));
        a3 += (double)(w * bfbits2f(v.y & 0xffff0000u));
    }
    #pragma unroll
    for (int ofs = 32; ofs >= HC; ofs >>= 1) {
        a0 += __shfl_down(a0, ofs); a1 += __shfl_down(a1, ofs);
        a2 += __shfl_down(a2, ofs); a3 += __shfl_down(a3, ofs);
    }
    if (lane < HC) {
        size_t o = (size_t)d * H + c4 * 4;
        float v0 = re.base[o] + (float)a0, v1 = re.base[o + 1] + (float)a1;
        float v2 = re.base[o + 2] + (float)a2, v3 = re.base[o + 3] + (float)a3;
        if (RELU) {
            v0 = fmaxf(v0, 0.f); v1 = fmaxf(v1, 0.f);
            v2 = fmaxf(v2, 0.f); v3 = fmaxf(v3, 0.f);
        }
        re.base[o] = v0; re.base[o + 1] = v1; re.base[o + 2] = v2; re.base[o + 3] = v3;
        if (RELU) {
            re.bfout[o] = f2bf(v0); re.bfout[o + 1] = f2bf(v1);
            re.bfout[o + 2] = f2bf(v2); re.bfout[o + 3] = f2bf(v3);
        }
    }
}

// column partial sums of x2_o -> part[block][32] (plain stores, deterministic)
__global__ void k_mean(const float* __restrict__ x2o, float* __restrict__ part) {
    __shared__ float s[256];
    int t = threadIdx.x; int hh = t & 31; int g = t >> 5;
    float acc = 0.f;
    for (int n = blockIdx.x * 8 + g; n < NN; n += gridDim.x * 8)
        acc += x2o[(size_t)n * 32 + hh];
    s[t] = acc;
    __syncthreads();
    if (t < 32) {
        float v = 0.f;
        for (int gg = 0; gg < 8; gg++) v += s[gg * 32 + t];
        part[blockIdx.x * 32 + t] = v;
    }
}

// MERGED final stage: blocks [0,NCLSB) = pair classifier; blocks [NCLSB,..)
// = discriminator. Each disc block recomputes csum from part locally
// (deterministic fixed-order; replaces the k_csum launch).
__launch_bounds__(256, 2)
__global__ void k_dc(const float* __restrict__ h1o, const float* __restrict__ x2o,
                     const float* __restrict__ feat, const float* __restrict__ attt,
                     const int* __restrict__ idx,
                     const unsigned short* __restrict__ cwt,
                     const float* __restrict__ clsb, float* __restrict__ log_out,
                     const float* __restrict__ part,
                     const float* __restrict__ x2a, const float* __restrict__ x2aa,
                     const float* __restrict__ discW, const float* __restrict__ discb,
                     float* ret_os, float* ret_osa) {
    int tid = threadIdx.x;
    if (blockIdx.x < NCLSB) {
        // ---- classifier role ----
        constexpr int LDK = CLS_CK + 8;
        __shared__ unsigned short As[CLS_BM][LDK];
        __shared__ unsigned short Bs[CLS_N][LDK];
        __shared__ int nd[2][CLS_BM];

        int p0 = blockIdx.x * CLS_BM;
        if (tid < CLS_BM) {
            nd[0][tid] = idx[p0 + tid];
            nd[1][tid] = idx[BB + p0 + tid];
        }
        float a0 = attt[0], a1 = attt[1];

        const int wave = tid >> 6;
        const int lane = tid & 63;
        const int q = lane >> 4;
        const int ln = lane & 15;
        constexpr int NT = CLS_N / 16;
        const int mbase = wave * 16;

        floatx4 acc[NT];
        #pragma unroll
        for (int nt = 0; nt < NT; nt++) acc[nt] = floatx4{0.f, 0.f, 0.f, 0.f};

        for (int ch = 0; ch < CLS_K / CLS_CK; ch++) {
            int kbase = ch * CLS_CK;
            __syncthreads();
            for (int c = tid; c < CLS_N * CLS_CK / 8; c += 256) {
                int row = c / (CLS_CK / 8), cc = c % (CLS_CK / 8);
                *(uint4*)&Bs[row][cc * 8] = *(const uint4*)&cwt[(size_t)row * CLS_K + kbase + cc * 8];
            }
            for (int c = tid; c < CLS_BM * CLS_CK / 4; c += 256) {
                int row = c / (CLS_CK / 4);
                int j4 = (c % (CLS_CK / 4)) * 4;
                int j = kbase + j4;
                float4 v = {0.f, 0.f, 0.f, 0.f};
                if (j < 448) {
                    int hseg = j / 224, jj = j % 224;
                    int node = nd[hseg][row];
                    if (jj < 64) {
                        v = *(const float4*)&h1o[(size_t)node * 64 + jj];
                        v.x *= a0; v.y *= a0; v.z *= a0; v.w *= a0;
                    } else if (jj < 96) {
                        v = *(const float4*)&x2o[(size_t)node * 32 + (jj - 64)];
                        v.x *= a1; v.y *= a1; v.z *= a1; v.w *= a1;
                    } else {
                        v = *(const float4*)&feat[(size_t)node * 128 + (jj - 96)];
                    }
                }
                uint2 pk;
                pk.x = (unsigned)f2bf(v.x) | ((unsigned)f2bf(v.y) << 16);
                pk.y = (unsigned)f2bf(v.z) | ((unsigned)f2bf(v.w) << 16);
                *(uint2*)&As[row][j4] = pk;
            }
            __syncthreads();
            #pragma unroll
            for (int ks = 0; ks < CLS_CK / 32; ks++) {
                int kk = ks * 32 + q * 8;
                short8 af = *(const short8*)&As[mbase + ln][kk];
                #pragma unroll
                for (int nt = 0; nt < NT; nt++) {
                    short8 bf = *(const short8*)&Bs[nt * 16 + ln][kk];
                    acc[nt] = __builtin_amdgcn_mfma_f32_16x16x32_bf16(af, bf, acc[nt], 0, 0, 0);
                }
            }
        }

        #pragma unroll
        for (int rr2 = 0; rr2 < 4; rr2++) {
            int i = mbase + q * 4 + rr2;
            int pair = p0 + i;
            #pragma unroll
            for (int nt = 0; nt < NT; nt++) {
                int col = nt * 16 + ln;
                if (col < RR)
                    log_out[(size_t)pair * RR + col] = acc[nt][rr2] + clsb[col];
            }
        }
        return;
    }

    // ---- discriminator role (csum computed locally, fixed order) ----
    __shared__ double sd[256];
    __shared__ float c[32], v[32];
    {
        int g = tid >> 5, hh = tid & 31;
        double a = 0.0;
        for (int k = 0; k < 32; k++) a += (double)part[(size_t)(k * 8 + g) * 32 + hh];
        sd[tid] = a;
        __syncthreads();
        if (tid < 32) {
            double a2 = 0.0;
            for (int gg = 0; gg < 8; gg++) a2 += sd[gg * 32 + tid];
            c[tid] = 1.f / (1.f + expf(-(float)a2 * (1.f / NN)));
        }
        __syncthreads();
        if (tid < 32) {
            float a3 = 0.f;
            for (int j = 0; j < 32; j++) a3 += discW[tid * 32 + j] * c[j];
            v[tid] = a3;
        }
        __syncthreads();
    }
    float db = discb[0];
    int n = (blockIdx.x - NCLSB) * 256 + tid;
    if (n < NN) {
        float s1 = 0.f, s2 = 0.f, s3 = 0.f;
        for (int j = 0; j < 32; j++) {
            float vj = v[j];
            s1 += x2o[(size_t)n * 32 + j] * vj;
            s2 += x2a[(size_t)n * 32 + j] * vj;
            s3 += x2aa[(size_t)n * 32 + j] * vj;
        }
        ret_os[n * 2] = s1 + db;  ret_os[n * 2 + 1] = s2 + db;
        ret_osa[n * 2] = s1 + db; ret_osa[n * 2 + 1] = s3 + db;
    }
}

extern "C" void kernel_launch(void* const* d_in, const int* in_sizes, int n_in,
                              void* d_out, int out_size, void* d_ws, size_t ws_size,
                              hipStream_t stream) {
    const float* x_o   = (const float*)d_in[0];
    const float* x_a   = (const float*)d_in[1];
    const float* feat  = (const float*)d_in[2];
    const float* W1    = (const float*)d_in[3];
    const float* root1 = (const float*)d_in[4];
    const float* b1    = (const float*)d_in[5];
    const float* W2    = (const float*)d_in[6];
    const float* root2 = (const float*)d_in[7];
    const float* b2    = (const float*)d_in[8];
    const float* attt  = (const float*)d_in[9];
    const float* discW = (const float*)d_in[10];
    const float* discb = (const float*)d_in[11];
    const float* clsW  = (const float*)d_in[12];
    const float* clsb  = (const float*)d_in[13];
    const int* ei      = (const int*)d_in[14];
    const int* et0     = (const int*)d_in[15];
    const int* et1     = (const int*)d_in[16];
    const int* idx     = (const int*)d_in[17];

    char* ws = (char*)d_ws;
    int* cntD  = (int*)(ws + OFF_CNTD);
    int* dstOff = (int*)(ws + OFF_DSTOFF);
    int* bh0   = (int*)(ws + OFF_BH0);
    int* bh1   = (int*)(ws + OFF_BH1);
    int* bb0   = (int*)(ws + OFF_BB0);
    int* bb1   = (int*)(ws + OFF_BB1);
    int* hT    = (int*)(ws + OFF_HT);
    int* offB0 = (int*)(ws + OFF_OFFB0);
    int* offB1 = (int*)(ws + OFF_OFFB1);
    int* tilB0 = (int*)(ws + OFF_TILB0);
    int* tilT0 = (int*)(ws + OFF_TILT0);
    int* tilB1 = (int*)(ws + OFF_TILB1);
    int* tilT1 = (int*)(ws + OFF_TILT1);
    int* slotE = (int*)(ws + OFF_SLOT);
    int* posD  = (int*)(ws + OFF_POSD);
    unsigned int* rdP = (unsigned int*)(ws + OFF_RDP);
    float* wD0 = (float*)(ws + OFF_WD0);
    float* wD1 = (float*)(ws + OFF_WD1);
    unsigned int* perm0 = (unsigned int*)(ws + OFF_PERM0);
    unsigned int* perm1 = (unsigned int*)(ws + OFF_PERM1);
    unsigned short* xob = (unsigned short*)(ws + OFF_XOB);
    unsigned short* xab = (unsigned short*)(ws + OFF_XAB);
    float* h1o  = (float*)(ws + OFF_H1);
    float* h1a  = h1o + (size_t)NN * HH1;
    float* h1aa = h1a + (size_t)NN * HH1;
    unsigned short* h1bo  = (unsigned short*)(ws + OFF_H1B);
    unsigned short* h1ba  = h1bo + (size_t)NN * HH1;
    unsigned short* h1baa = h1ba + (size_t)NN * HH1;
    float* x2a  = (float*)(ws + OFF_X2A);
    float* x2aa = (float*)(ws + OFF_X2AA);
    unsigned short* w1t = (unsigned short*)(ws + OFF_W1BT);
    unsigned short* w2t = (unsigned short*)(ws + OFF_W2BT);
    unsigned short* r1t = (unsigned short*)(ws + OFF_R1T);
    unsigned short* r2t = (unsigned short*)(ws + OFF_R2T);
    unsigned short* cwt = (unsigned short*)(ws + OFF_CWT);
    float* part = (float*)(ws + OFF_PART);
    unsigned short* msg = (unsigned short*)(ws + OFF_MSG);

    float* out = (float*)d_out;
    float* log_out = out + O_LOG;
    float* ret_os  = out + O_ROS;
    float* ret_osa = out + O_ROSA;
    float* x2o     = out + O_X2O;

    size_t availMsg = ws_size > OFF_MSG ? ws_size - OFF_MSG : MSG_B1;
    int nb1 = (availMsg >= 3 * MSG_B1) ? 3 : (availMsg >= 2 * MSG_B1 ? 2 : 1);
    int nb2 = (availMsg >= 3 * MSG_B2) ? 3 : (availMsg >= 2 * MSG_B2 ? 2 : 1);

    // 1) zero control block (csum + cntD) — ~80 KB
    hipMemsetAsync(ws, 0, ZERO_BYTES, stream);

    // 2) preprocessing (4 launches: hist, A, B, C)
    k_hist<<<GRID_PRE, 256, 0, stream>>>(ei, et0, et1, cntD, slotE, bh0, bh1,
                                         x_o, x_a, W1, W2, root1, root2, clsW,
                                         xob, xab, w1t, w2t, r1t, r2t, cwt);
    k_scanA<<<1 + (2 * NB2 + 3) / 4, 256, 0, stream>>>(cntD, dstOff, bh0, bh1,
                                                       bb0, bb1, hT);
    k_postB<<<2501, 256, 0, stream>>>(ei, et0, et1, dstOff, slotE, posD, rdP,
                                      hT, offB0, offB1, tilB0, tilT0, tilB1, tilT1);
    k_fillC<<<NBH + NN / 4, 256, 0, stream>>>(ei, et0, et1, posD, offB0, offB1,
                                              bb0, bb1, perm0, perm1,
                                              dstOff, rdP, wD0, wD1);

    const unsigned short* X1s[3] = {xob, xab, xob};
    float* O1s[3] = {h1o, h1a, h1aa};
    unsigned short* O1bs[3] = {h1bo, h1ba, h1baa};
    const unsigned short* X2s[3] = {h1bo, h1ba, h1baa};
    float* O2s[3] = {x2o, x2a, x2aa};

    // 3) layer 1
    if (nb1 >= 3) {
        GemmArgs ga{};
        RedArgs ra{};
        for (int enc = 0; enc < 3; enc++) {
            unsigned short* mb = msg + (size_t)enc * EE * HH1;
            ga.e[enc] = GemmEnc{X1s[enc], mb, enc == 2 ? perm1 : perm0,
                                enc == 2 ? offB1 : offB0, enc == 2 ? tilB1 : tilB0,
                                enc == 2 ? tilT1 : tilT0, O1s[enc]};
            ra.e[enc] = RedEnc{mb, enc == 2 ? wD1 : wD0, O1s[enc], O1bs[enc]};
        }
        k_mgemm<FIN1, HH1><<<dim3(NBT + MAXT2, 3), 512, 0, stream>>>(ga, w1t, r1t, b1);
        k_reduce<HH1, true><<<dim3(NN / 4, 3), 256, 0, stream>>>(ra, dstOff);
    } else {
        dim3 gb(NBT, 3);
        k_bgemm<FIN1, HH1><<<gb, 256, 0, stream>>>(xob, xab, xob, r1t, b1,
                                                   h1o, h1a, h1aa);
        for (int e0 = 0; e0 < 3; ) {
            int g = 3 - e0 < nb1 ? 3 - e0 : nb1;
            GemmArgs ga{};
            RedArgs ra{};
            for (int j = 0; j < g; j++) {
                int enc = e0 + j;
                unsigned short* mb = msg + (size_t)j * EE * HH1;
                ga.e[j] = GemmEnc{X1s[enc], mb, enc == 2 ? perm1 : perm0,
                                  enc == 2 ? offB1 : offB0, enc == 2 ? tilB1 : tilB0,
                                  enc == 2 ? tilT1 : tilT0, O1s[enc]};
                ra.e[j] = RedEnc{mb, enc == 2 ? wD1 : wD0, O1s[enc], O1bs[enc]};
            }
            k_gemm<FIN1, HH1><<<dim3(MAXT2, g), 512, 0, stream>>>(ga, w1t);
            k_reduce<HH1, true><<<dim3(NN / 4, g), 256, 0, stream>>>(ra, dstOff);
            e0 += g;
        }
    }

    // 4) layer 2
    if (nb2 >= 3) {
        GemmArgs ga{};
        RedArgs ra{};
        for (int enc = 0; enc < 3; enc++) {
            unsigned short* mb = msg + (size_t)enc * EE * HH2;
            ga.e[enc] = GemmEnc{X2s[enc], mb, enc == 2 ? perm1 : perm0,
                                enc == 2 ? offB1 : offB0, enc == 2 ? tilB1 : tilB0,
                                enc == 2 ? tilT1 : tilT0, O2s[enc]};
            ra.e[enc] = RedEnc{mb, enc == 2 ? wD1 : wD0, O2s[enc], nullptr};
        }
        k_mgemm<HH1, HH2><<<dim3(NBT + MAXT2, 3), 512, 0, stream>>>(ga, w2t, r2t, b2);
        k_reduce<HH2, false><<<dim3(NN / 4, 3), 256, 0, stream>>>(ra, dstOff);
    } else {
        dim3 gb(NBT, 3);
        k_bgemm<HH1, HH2><<<gb, 256, 0, stream>>>(h1bo, h1ba, h1baa, r2t, b2,
                                                  x2o, x2a, x2aa);
        for (int e0 = 0; e0 < 3; ) {
            int g = 3 - e0 < nb2 ? 3 - e0 : nb2;
            GemmArgs ga{};
            RedArgs ra{};
            for (int j = 0; j < g; j++) {
                int enc = e0 + j;
                unsigned short* mb = msg + (size_t)j * EE * HH2;
                ga.e[j] = GemmEnc{X2s[enc], mb, enc == 2 ? perm1 : perm0,
                                  enc == 2 ? offB1 : offB0, enc == 2 ? tilB1 : tilB0,
                                  enc == 2 ? tilT1 : tilT0, O2s[enc]};
                ra.e[j] = RedEnc{mb, enc == 2 ? wD1 : wD0, O2s[enc], nullptr};
            }
            k_gemm<HH1, HH2><<<dim3(MAXT2, g), 512, 0, stream>>>(ga, w2t);
            k_reduce<HH2, false><<<dim3(NN / 4, g), 256, 0, stream>>>(ra, dstOff);
            e0 += g;
        }
    }

    // 5) readout + merged discriminator/classifier
    k_mean<<<256, 256, 0, stream>>>(x2o, part);
    k_dc<<<NCLSB + NDISCB, 256, 0, stream>>>(h1o, x2o, feat, attt, idx, cwt, clsb,
                                             log_out, part, x2a, x2aa, discW, discb,
                                             ret_os, ret_osa);
}